// Round 13
// baseline (16124.191 us; speedup 1.0000x reference)
//
#include <hip/hip_runtime.h>

// ---------------- problem constants ----------------
#define B_ 8
#define S_ 128
#define H_ 512
#define G_ 2048   // 4H
#define MEL_ 80

// ---------------- ws layout (32-bit word offsets) ----------------
// decoder flags per batch (1024 words): C lines 0..7 (slice), B line 8
#define FLG_DEC    0                    // 8 * 1024 = 8192
#define FLG_L0     8192                 // 16 groups * 128 words
#define FLG_L1     10240
#define OFF_H0S    12288                // lstm0 h [(dir*8+b)][2][512] = 16384
#define OFF_H1S    28672                // 16384
#define OFF_DH     45056                // dec h [2][b][512] = 8192 (ping-pong)
#define OFF_ATT    53248                // att [b][128] = 1024
#define OFF_HW     54272                // (unused) 4096
#define ZERO_WORDS 58368                // = 228*256
#define OFF_X0     58368                        // [bs][512]   524288
#define OFF_GX0F   (OFF_X0 + 524288)            // [bs][2048] 2097152  (-> WE after lstm1)
#define OFF_GX0B   (OFF_GX0F + 2097152)         // (-> WH2 + biases after lstm0)
#define OFF_H0     (OFF_GX0B + 2097152)         // [bs][1024] 1048576
#define OFF_GX1F   (OFF_H0 + 1048576)
#define OFF_GX1B   (OFF_GX1F + 2097152)
#define OFF_ENC    (OFF_GX1B + 2097152)         // [bs][1024] 1048576
#define OFF_ENCP   (OFF_ENC + 1048576)          // [bs][512]   524288
// precomputed regions (reuse dead GX0 buffers)
#define OFF_WE     OFF_GX0F                     // [b][2048][128] = 2097152
#define OFF_WH2    OFF_GX0B                     // [2048][512] = 1048576
#define OFF_BA     (OFF_GX0B + 1048576)         // 2048
#define OFF_BB     (OFF_GX0B + 1050624)         // 2048

// ---------------- helpers ----------------
__device__ __forceinline__ float sigm_f(float x) {
    x = fminf(fmaxf(x, -30.f), 30.f);
    return 1.f / (1.f + __expf(-x));
}
__device__ __forceinline__ float tanh_f(float x) {
    x = fminf(fmaxf(x, -15.f), 15.f);
    float e = __expf(2.f * x);
    return (e - 1.f) / (e + 1.f);
}

// device-scope uncached scalar access (bypasses caches w/o invalidating them)
__device__ __forceinline__ void agw_u(unsigned* p, unsigned v) {
    __hip_atomic_store(p, v, __ATOMIC_RELAXED, __HIP_MEMORY_SCOPE_AGENT);
}
__device__ __forceinline__ unsigned agr_u(const unsigned* p) {
    return __hip_atomic_load(p, __ATOMIC_RELAXED, __HIP_MEMORY_SCOPE_AGENT);
}
__device__ __forceinline__ void agw_f(float* p, float v) {
    agw_u((unsigned*)p, __float_as_uint(v));
}

// device-coherent VECTOR load (sc1): 16B analog of agent-scope atomic load
__device__ __forceinline__ float4 agr_f4(const float* p) {
    float4 v;
    asm volatile("global_load_dwordx4 %0, %1, off sc1\n\t"
                 "s_waitcnt vmcnt(0)"
                 : "=v"(v) : "v"(p) : "memory");
    return v;
}

// ---------------- zero init ----------------
__global__ __launch_bounds__(256) void zero_kernel(float* p) {
    p[blockIdx.x * 256 + threadIdx.x] = 0.f;
}

// ---------------- embedding ----------------
__global__ __launch_bounds__(256) void embed_kernel(const int* __restrict__ text,
                                                    const float* __restrict__ emb,
                                                    float* __restrict__ X) {
    int i = blockIdx.x * 256 + threadIdx.x;
    int bs = i >> 7;
    int h4 = i & 127;
    int ch = text[bs];
    ((float4*)X)[i] = ((const float4*)emb)[ch * 128 + h4];
}

// ---------------- f32 GEMM: C[M,N] = A[M,K] * W[N,K]^T + b1 (+ b2) ----------------
__global__ __launch_bounds__(256) void gemm_f32(const float* __restrict__ A, int lda,
                                                const float* __restrict__ W, int ldw,
                                                const float* __restrict__ b1,
                                                const float* __restrict__ b2,
                                                float* __restrict__ C, int ldc, int K) {
    __shared__ float As[32][68];
    __shared__ float Ws[32][68];
    int tid = threadIdx.x;
    int tx = tid & 15, ty = tid >> 4;
    int n0 = blockIdx.x * 64, m0 = blockIdx.y * 64;
    float acc[4][4] = {};
    int r  = tid >> 3;
    int c4 = (tid & 7) * 4;
    for (int k0 = 0; k0 < K; k0 += 32) {
        float4 a0 = *(const float4*)&A[(m0 + r) * lda + k0 + c4];
        float4 a1 = *(const float4*)&A[(m0 + r + 32) * lda + k0 + c4];
        float4 w0 = *(const float4*)&W[(n0 + r) * ldw + k0 + c4];
        float4 w1 = *(const float4*)&W[(n0 + r + 32) * ldw + k0 + c4];
        As[c4 + 0][r] = a0.x; As[c4 + 1][r] = a0.y; As[c4 + 2][r] = a0.z; As[c4 + 3][r] = a0.w;
        As[c4 + 0][r + 32] = a1.x; As[c4 + 1][r + 32] = a1.y; As[c4 + 2][r + 32] = a1.z; As[c4 + 3][r + 32] = a1.w;
        Ws[c4 + 0][r] = w0.x; Ws[c4 + 1][r] = w0.y; Ws[c4 + 2][r] = w0.z; Ws[c4 + 3][r] = w0.w;
        Ws[c4 + 0][r + 32] = w1.x; Ws[c4 + 1][r + 32] = w1.y; Ws[c4 + 2][r + 32] = w1.z; Ws[c4 + 3][r + 32] = w1.w;
        __syncthreads();
#pragma unroll 8
        for (int kk = 0; kk < 32; ++kk) {
            float4 av = *(const float4*)&As[kk][ty * 4];
            float4 wv = *(const float4*)&Ws[kk][tx * 4];
            acc[0][0] = fmaf(av.x, wv.x, acc[0][0]); acc[0][1] = fmaf(av.x, wv.y, acc[0][1]);
            acc[0][2] = fmaf(av.x, wv.z, acc[0][2]); acc[0][3] = fmaf(av.x, wv.w, acc[0][3]);
            acc[1][0] = fmaf(av.y, wv.x, acc[1][0]); acc[1][1] = fmaf(av.y, wv.y, acc[1][1]);
            acc[1][2] = fmaf(av.y, wv.z, acc[1][2]); acc[1][3] = fmaf(av.y, wv.w, acc[1][3]);
            acc[2][0] = fmaf(av.z, wv.x, acc[2][0]); acc[2][1] = fmaf(av.z, wv.y, acc[2][1]);
            acc[2][2] = fmaf(av.z, wv.z, acc[2][2]); acc[2][3] = fmaf(av.z, wv.w, acc[2][3]);
            acc[3][0] = fmaf(av.w, wv.x, acc[3][0]); acc[3][1] = fmaf(av.w, wv.y, acc[3][1]);
            acc[3][2] = fmaf(av.w, wv.z, acc[3][2]); acc[3][3] = fmaf(av.w, wv.w, acc[3][3]);
        }
        __syncthreads();
    }
#pragma unroll
    for (int i = 0; i < 4; ++i)
#pragma unroll
        for (int j = 0; j < 4; ++j) {
            int n = n0 + tx * 4 + j;
            int m = m0 + ty * 4 + i;
            float bias = (b1 ? b1[n] : 0.f) + (b2 ? b2[n] : 0.f);
            C[m * ldc + n] = acc[i][j] + bias;
        }
}

// ---------------- WE[b][r][s] = Wih_ctx[r] . ENC_b[s]  (K=1024) ----------------
__global__ __launch_bounds__(256) void we_kernel(const float* __restrict__ Wih,
                                                 const float* __restrict__ ENC,
                                                 float* __restrict__ WE) {
    const float* A = Wih + 80;                          // [2048][1024], lda 1104
    const float* W = ENC + (size_t)blockIdx.z * 131072; // [128][1024]
    float* C = WE + (size_t)blockIdx.z * 262144;        // [2048][128]
    __shared__ float As[32][68];
    __shared__ float Ws[32][68];
    int tid = threadIdx.x;
    int tx = tid & 15, ty = tid >> 4;
    int n0 = blockIdx.x * 64, m0 = blockIdx.y * 64;
    float acc[4][4] = {};
    int r  = tid >> 3;
    int c4 = (tid & 7) * 4;
    for (int k0 = 0; k0 < 1024; k0 += 32) {
        float4 a0 = *(const float4*)&A[(size_t)(m0 + r) * 1104 + k0 + c4];
        float4 a1 = *(const float4*)&A[(size_t)(m0 + r + 32) * 1104 + k0 + c4];
        float4 w0 = *(const float4*)&W[(n0 + r) * 1024 + k0 + c4];
        float4 w1 = *(const float4*)&W[(n0 + r + 32) * 1024 + k0 + c4];
        As[c4 + 0][r] = a0.x; As[c4 + 1][r] = a0.y; As[c4 + 2][r] = a0.z; As[c4 + 3][r] = a0.w;
        As[c4 + 0][r + 32] = a1.x; As[c4 + 1][r + 32] = a1.y; As[c4 + 2][r + 32] = a1.z; As[c4 + 3][r + 32] = a1.w;
        Ws[c4 + 0][r] = w0.x; Ws[c4 + 1][r] = w0.y; Ws[c4 + 2][r] = w0.z; Ws[c4 + 3][r] = w0.w;
        Ws[c4 + 0][r + 32] = w1.x; Ws[c4 + 1][r + 32] = w1.y; Ws[c4 + 2][r + 32] = w1.z; Ws[c4 + 3][r + 32] = w1.w;
        __syncthreads();
#pragma unroll 8
        for (int kk = 0; kk < 32; ++kk) {
            float4 av = *(const float4*)&As[kk][ty * 4];
            float4 wv = *(const float4*)&Ws[kk][tx * 4];
            acc[0][0] = fmaf(av.x, wv.x, acc[0][0]); acc[0][1] = fmaf(av.x, wv.y, acc[0][1]);
            acc[0][2] = fmaf(av.x, wv.z, acc[0][2]); acc[0][3] = fmaf(av.x, wv.w, acc[0][3]);
            acc[1][0] = fmaf(av.y, wv.x, acc[1][0]); acc[1][1] = fmaf(av.y, wv.y, acc[1][1]);
            acc[1][2] = fmaf(av.y, wv.z, acc[1][2]); acc[1][3] = fmaf(av.y, wv.w, acc[1][3]);
            acc[2][0] = fmaf(av.z, wv.x, acc[2][0]); acc[2][1] = fmaf(av.z, wv.y, acc[2][1]);
            acc[2][2] = fmaf(av.z, wv.z, acc[2][2]); acc[2][3] = fmaf(av.z, wv.w, acc[2][3]);
            acc[3][0] = fmaf(av.w, wv.x, acc[3][0]); acc[3][1] = fmaf(av.w, wv.y, acc[3][1]);
            acc[3][2] = fmaf(av.w, wv.z, acc[3][2]); acc[3][3] = fmaf(av.w, wv.w, acc[3][3]);
        }
        __syncthreads();
    }
#pragma unroll
    for (int i = 0; i < 4; ++i)
#pragma unroll
        for (int j = 0; j < 4; ++j)
            C[(size_t)(m0 + ty * 4 + i) * 128 + n0 + tx * 4 + j] = acc[i][j];
}

// ---------------- WH2 = dec_Whh + Wih[:,:80] @ mel_W ----------------
__global__ __launch_bounds__(256) void wh2_kernel(const float* __restrict__ Wih,
                                                  const float* __restrict__ Whh,
                                                  const float* __restrict__ melW,
                                                  float* __restrict__ WH2) {
    int wg = blockIdx.x;
    int tid = threadIdx.x;
    int r = wg >> 1;
    int k = (wg & 1) * 256 + tid;
    __shared__ float wrow[80];
    if (tid < 80) wrow[tid] = Wih[(size_t)r * 1104 + tid];
    __syncthreads();
    float acc = Whh[(size_t)r * 512 + k];
#pragma unroll 8
    for (int m = 0; m < 80; ++m)
        acc = fmaf(wrow[m], melW[m * 512 + k], acc);
    WH2[(size_t)r * 512 + k] = acc;
}

// ---------------- biasA = bih+bhh ; biasB = biasA + Wih[:,:80].mel_b ----------------
__global__ __launch_bounds__(256) void bias_kernel(const float* __restrict__ Wih,
                                                   const float* __restrict__ bih,
                                                   const float* __restrict__ bhh,
                                                   const float* __restrict__ melb,
                                                   float* __restrict__ BA,
                                                   float* __restrict__ BB) {
    int r = blockIdx.x * 256 + threadIdx.x;
    float a = bih[r] + bhh[r];
    float b2 = 0.f;
#pragma unroll 8
    for (int m = 0; m < 80; ++m)
        b2 = fmaf(Wih[(size_t)r * 1104 + m], melb[m], b2);
    BA[r] = a;
    BB[r] = a + b2;
}

// ---------------- per-(dir,batch) LSTM: slice-major + pipelined stage + fast flag ----
__global__ __launch_bounds__(256) void lstm_kernel(const float* __restrict__ GXf,
                                                   const float* __restrict__ GXb,
                                                   const float* __restrict__ Whh_f,
                                                   const float* __restrict__ Whh_b,
                                                   float* __restrict__ Hout,
                                                   float* __restrict__ hstate,
                                                   unsigned* __restrict__ flagsL) {
    int wg  = blockIdx.x;
    int s   = wg & 7;
    int g16 = wg >> 3;
    int dir = g16 >> 3;
    int b   = g16 & 7;
    const float* GX  = dir ? GXb : GXf;
    const float* Whh = dir ? Whh_b : Whh_f;
    float* hs = hstate + g16 * 1024;         // [2][512]
    unsigned* fg = flagsL + g16 * 128;       // 8 flag lines

    int tid = threadIdx.x;
    int g = tid >> 6, c = tid & 63;
    int grow = g * 512 + s * 64 + c;
    const float* wr = Whh + (size_t)grow * 512;

    __shared__ float hsh[512];
    __shared__ float gvL[4][64];

    float cst = 0.f;

    for (int t = 0; t < 128; ++t) {
        // pipelined poll+stage: lane waits only on its own producer
        if (tid < 128) {
            const unsigned* f = fg + (tid >> 4) * 16;
            while (agr_u(f) < (unsigned)t)
                __builtin_amdgcn_s_sleep(1);
            *(float4*)&hsh[tid * 4] = agr_f4(hs + (t & 1) * 512 + tid * 4);
        }
        __syncthreads();

        int st = dir ? (127 - t) : t;
        float acc = GX[((size_t)b * S_ + st) * G_ + grow];
        float a0 = 0.f, a1 = 0.f, a2 = 0.f, a3 = 0.f;
#pragma unroll 8
        for (int k = 0; k < 512; k += 4) {
            float4 wv = *(const float4*)(wr + k);
            float4 hv = *(const float4*)&hsh[k];
            a0 = fmaf(wv.x, hv.x, a0); a1 = fmaf(wv.y, hv.y, a1);
            a2 = fmaf(wv.z, hv.z, a2); a3 = fmaf(wv.w, hv.w, a3);
        }
        gvL[g][c] = acc + (a0 + a1) + (a2 + a3);
        __syncthreads();

        // fast flag: wave 0 writes h, drains ITS stores, sets flag; no barrier
        if (tid < 64) {
            float gi = gvL[0][tid], gf = gvL[1][tid];
            float gg = gvL[2][tid], go = gvL[3][tid];
            float c2 = sigm_f(gf) * cst + sigm_f(gi) * tanh_f(gg);
            float h2 = sigm_f(go) * tanh_f(c2);
            cst = c2;
            agw_f(hs + ((t & 1) ^ 1) * 512 + s * 64 + tid, h2);
            asm volatile("s_waitcnt vmcnt(0)" ::: "memory");
            if (tid == 0)
                agw_u(fg + s * 16, (unsigned)(t + 1));
            Hout[((size_t)b * S_ + st) * 1024 + dir * 512 + s * 64 + tid] = h2;
        }
    }
}

// ---------------- decoder: folded gates, 2 edges/step, 72 WGs ----------------
// gate WG: wg = b*8+s -> XCD s: slice s = cols [s*64,(s+1)*64) x 4 gates (256
// rows, 1 row/thread). Streams WH2 slice (512KB, shared by 8 batches) + WE
// slice (128KB/batch). attn WG: wg = 64+b -> XCD b: hW (W_h 1MB L2-hot) +
// scores + softmax -> att; mel off-path. Per-XCD ~2.9MB.
// Step cycle: fC(8) [h_t] -> attn {hW, scores, softmax} -> fB [att] ->
// gates {WE.att + cell} -> fC.  Gates' WH2.h overlaps the attention phase.
__global__ __launch_bounds__(256) void decoder_kernel(float* __restrict__ ws,
                                                      const float* __restrict__ attn_W,
                                                      const float* __restrict__ attn_v,
                                                      const float* __restrict__ mel_W,
                                                      const float* __restrict__ mel_b,
                                                      float* __restrict__ out, int T,
                                                      unsigned* __restrict__ flags) {
    float* ENCP = ws + OFF_ENCP;
    float* DH   = ws + OFF_DH;    // [2][8][512]
    float* ATT  = ws + OFF_ATT;   // [8][128]
    const float* WE  = ws + OFF_WE;
    const float* WH2 = ws + OFF_WH2;
    const float* BA  = ws + OFF_BA;
    const float* BB  = ws + OFF_BB;

    int wg  = blockIdx.x;    // 0..71
    int tid = threadIdx.x;

    if (wg < 64) {
        // ================= gate WG (slice s, batch b) =================
        int s = wg & 7;
        int b = wg >> 3;
        unsigned* fC = flags + b * 1024;     // 8 lines
        unsigned* fB = fC + 8 * 16;          // line 8

        int g = tid >> 6, c = tid & 63;
        int grow = g * 512 + s * 64 + c;     // one gate-row per thread
        const float* wh2_row = WH2 + (size_t)grow * 512;
        const float* we_row  = WE + ((size_t)b * 2048 + grow) * 128;
        float bias_a = BA[grow];
        float bias_b = BB[grow];

        __shared__ float hsh[512];
        __shared__ float attL[128];
        __shared__ float gvL[4][64];

        float cst = 0.f;   // tid<64: col = s*64+tid

        for (int t = 0; t < T; ++t) {
            // ---- stage h_t (pipelined poll per producer) ----
            if (tid < 128) {
                const unsigned* f = fC + (tid >> 4) * 16;
                while (agr_u(f) < (unsigned)t)
                    __builtin_amdgcn_s_sleep(1);
                *(float4*)&hsh[tid * 4] = agr_f4(DH + (t & 1) * 4096 + b * 512 + tid * 4);
            }
            __syncthreads();

            // WH2.h (overlaps attention WG's hW+scores)
            float wpart = (t == 0) ? bias_a : bias_b;
            {
                float a0 = 0.f, a1 = 0.f, a2 = 0.f, a3 = 0.f;
#pragma unroll 8
                for (int k = 0; k < 512; k += 4) {
                    float4 wv = *(const float4*)(wh2_row + k);
                    float4 hv = *(const float4*)&hsh[k];
                    a0 = fmaf(wv.x, hv.x, a0); a1 = fmaf(wv.y, hv.y, a1);
                    a2 = fmaf(wv.z, hv.z, a2); a3 = fmaf(wv.w, hv.w, a3);
                }
                wpart += (a0 + a1) + (a2 + a3);
            }

            // ---- stage att (single producer flag) ----
            if (tid < 32) {
                while (agr_u(fB) < (unsigned)(t + 1))
                    __builtin_amdgcn_s_sleep(1);
                *(float4*)&attL[tid * 4] = agr_f4(ATT + b * 128 + tid * 4);
            }
            __syncthreads();

            // WE.att (K=128)
            {
                float a0 = 0.f, a1 = 0.f, a2 = 0.f, a3 = 0.f;
#pragma unroll 8
                for (int k = 0; k < 128; k += 4) {
                    float4 wv = *(const float4*)(we_row + k);
                    a0 = fmaf(wv.x, attL[k + 0], a0); a1 = fmaf(wv.y, attL[k + 1], a1);
                    a2 = fmaf(wv.z, attL[k + 2], a2); a3 = fmaf(wv.w, attL[k + 3], a3);
                }
                gvL[g][c] = wpart + (a0 + a1) + (a2 + a3);
            }
            __syncthreads();

            // cell + fast flag (wave 0 only)
            if (tid < 64) {
                float gi = gvL[0][tid], gf = gvL[1][tid];
                float gg = gvL[2][tid], go = gvL[3][tid];
                float c2 = sigm_f(gf) * cst + sigm_f(gi) * tanh_f(gg);
                float h2 = sigm_f(go) * tanh_f(c2);
                cst = c2;
                agw_f(DH + ((t + 1) & 1) * 4096 + b * 512 + s * 64 + tid, h2);
                asm volatile("s_waitcnt vmcnt(0)" ::: "memory");
                if (tid == 0)
                    agw_u(fC + s * 16, (unsigned)(t + 1));
            }
        }
    } else {
        // ================= attention WG (batch b) =================
        int b = wg - 64;
        unsigned* fC = flags + b * 1024;
        unsigned* fB = fC + 8 * 16;

        __shared__ float dh2[512];
        __shared__ float hw[512];
        __shared__ float scred[128][2];
        __shared__ float red[128];
        __shared__ float att[128];
        __shared__ float melp[80][2];

        int r = tid >> 1, half = tid & 1;

        for (int t = 0; t < T; ++t) {
            // stage h_t (pipelined)
            if (tid < 128) {
                const unsigned* f = fC + (tid >> 4) * 16;
                while (agr_u(f) < (unsigned)t)
                    __builtin_amdgcn_s_sleep(1);
                *(float4*)&dh2[tid * 4] = agr_f4(DH + (t & 1) * 4096 + b * 512 + tid * 4);
            }
            __syncthreads();

            // hW: rows tid, tid+256 (W_h = attn_W[:, :512], row stride 1536)
#pragma unroll
            for (int rr = 0; rr < 2; ++rr) {
                int row = tid + rr * 256;
                const float* wr = attn_W + (size_t)row * 1536;
                float a0 = 0.f, a1 = 0.f, a2 = 0.f, a3 = 0.f;
#pragma unroll 8
                for (int k = 0; k < 512; k += 4) {
                    float4 wv = *(const float4*)(wr + k);
                    float4 hv = *(const float4*)&dh2[k];
                    a0 = fmaf(wv.x, hv.x, a0); a1 = fmaf(wv.y, hv.y, a1);
                    a2 = fmaf(wv.z, hv.z, a2); a3 = fmaf(wv.w, hv.w, a3);
                }
                hw[row] = (a0 + a1) + (a2 + a3);
            }
            __syncthreads();

            // scores: sI = tid&127, k-half = tid>>7
            {
                int sI = tid & 127, kh = tid >> 7;
                const float* ep = ENCP + ((size_t)b * S_ + sI) * 512 + kh * 256;
                const float* hp = hw + kh * 256;
                const float* vv = attn_v + kh * 256;
                float a0 = 0.f, a1 = 0.f, a2 = 0.f, a3 = 0.f;
#pragma unroll 4
                for (int k = 0; k < 256; k += 4) {
                    float4 e4 = *(const float4*)(ep + k);
                    float4 h4 = *(const float4*)(hp + k);
                    float4 v4 = *(const float4*)(vv + k);
                    a0 = fmaf(tanh_f(e4.x + h4.x), v4.x, a0);
                    a1 = fmaf(tanh_f(e4.y + h4.y), v4.y, a1);
                    a2 = fmaf(tanh_f(e4.z + h4.z), v4.z, a2);
                    a3 = fmaf(tanh_f(e4.w + h4.w), v4.w, a3);
                }
                scred[sI][kh] = (a0 + a1) + (a2 + a3);
            }
            __syncthreads();

            float sc = 0.f;
            if (tid < 128) {
                sc = scred[tid][0] + scred[tid][1];
                red[tid] = sc;
            }
            __syncthreads();
            for (int off = 64; off >= 1; off >>= 1) {
                if (tid < off) red[tid] = fmaxf(red[tid], red[tid + off]);
                __syncthreads();
            }
            float mx = red[0];
            __syncthreads();
            if (tid < 128) {
                float e = __expf(sc - mx);
                att[tid] = e;
                red[tid] = e;
            }
            __syncthreads();
            if (tid < 64) red[tid] += red[tid + 64];
            __syncthreads();
            for (int off = 32; off >= 1; off >>= 1) {
                if (tid < off) red[tid] += red[tid + off];
                __syncthreads();
            }
            float inv = 1.f / red[0];

            // att write + fast flag: wave 0 only (lanes 0..31 store 4 each)
            if (tid < 32) {
                agw_f(ATT + b * 128 + tid * 4 + 0, att[tid * 4 + 0] * inv);
                agw_f(ATT + b * 128 + tid * 4 + 1, att[tid * 4 + 1] * inv);
                agw_f(ATT + b * 128 + tid * 4 + 2, att[tid * 4 + 2] * inv);
                agw_f(ATT + b * 128 + tid * 4 + 3, att[tid * 4 + 3] * inv);
                asm volatile("s_waitcnt vmcnt(0)" ::: "memory");
                if (tid == 0)
                    agw_u(fB, (unsigned)(t + 1));
            }

            // ---- off-critical-path: mel from h_t (already in dh2) -> out[t-1] ----
            if (t > 0) {
                if (tid < 160) {
                    const float* wp = mel_W + (size_t)r * 512 + half * 256;
                    const float* hp = dh2 + half * 256;
                    float a0 = 0.f, a1 = 0.f, a2 = 0.f, a3 = 0.f;
#pragma unroll 8
                    for (int k = 0; k < 256; k += 4) {
                        float4 wv = *(const float4*)(wp + k);
                        float4 hv = *(const float4*)(hp + k);
                        a0 = fmaf(wv.x, hv.x, a0); a1 = fmaf(wv.y, hv.y, a1);
                        a2 = fmaf(wv.z, hv.z, a2); a3 = fmaf(wv.w, hv.w, a3);
                    }
                    melp[r][half] = (a0 + a1) + (a2 + a3);
                }
                __syncthreads();    // also separates dh2 reads from next-step stage
                if (tid < 80)
                    out[b * MEL_ * T + tid * T + (t - 1)] = melp[tid][0] + melp[tid][1] + mel_b[tid];
            } else {
                __syncthreads();
            }
        }

        // epilogue: final mel from h_T -> out[T-1]
        if (tid < 128) {
            const unsigned* f = fC + (tid >> 4) * 16;
            while (agr_u(f) < (unsigned)T)
                __builtin_amdgcn_s_sleep(1);
            *(float4*)&dh2[tid * 4] = agr_f4(DH + (T & 1) * 4096 + b * 512 + tid * 4);
        }
        __syncthreads();
        if (tid < 160) {
            const float* wp = mel_W + (size_t)r * 512 + half * 256;
            const float* hp = dh2 + half * 256;
            float a0 = 0.f, a1 = 0.f, a2 = 0.f, a3 = 0.f;
#pragma unroll 8
            for (int k = 0; k < 256; k += 4) {
                float4 wv = *(const float4*)(wp + k);
                float4 hv = *(const float4*)(hp + k);
                a0 = fmaf(wv.x, hv.x, a0); a1 = fmaf(wv.y, hv.y, a1);
                a2 = fmaf(wv.z, hv.z, a2); a3 = fmaf(wv.w, hv.w, a3);
            }
            melp[r][half] = (a0 + a1) + (a2 + a3);
        }
        __syncthreads();
        if (tid < 80)
            out[b * MEL_ * T + tid * T + (T - 1)] = melp[tid][0] + melp[tid][1] + mel_b[tid];
    }
}

// ---------------- host launch ----------------
extern "C" void kernel_launch(void* const* d_in, const int* in_sizes, int n_in,
                              void* d_out, int out_size, void* d_ws, size_t ws_size,
                              hipStream_t stream) {
    const int*   text  = (const int*)d_in[0];
    const float* emb   = (const float*)d_in[2];
    const float* Wih00 = (const float*)d_in[3];
    const float* Whh00 = (const float*)d_in[4];
    const float* bih00 = (const float*)d_in[5];
    const float* bhh00 = (const float*)d_in[6];
    const float* Wih01 = (const float*)d_in[7];
    const float* Whh01 = (const float*)d_in[8];
    const float* bih01 = (const float*)d_in[9];
    const float* bhh01 = (const float*)d_in[10];
    const float* Wih10 = (const float*)d_in[11];
    const float* Whh10 = (const float*)d_in[12];
    const float* bih10 = (const float*)d_in[13];
    const float* bhh10 = (const float*)d_in[14];
    const float* Wih11 = (const float*)d_in[15];
    const float* Whh11 = (const float*)d_in[16];
    const float* bih11 = (const float*)d_in[17];
    const float* bhh11 = (const float*)d_in[18];
    const float* attn_W = (const float*)d_in[19];
    const float* attn_b = (const float*)d_in[20];
    const float* attn_v = (const float*)d_in[21];
    const float* dec_Wih = (const float*)d_in[22];
    const float* dec_Whh = (const float*)d_in[23];
    const float* dec_bih = (const float*)d_in[24];
    const float* dec_bhh = (const float*)d_in[25];
    const float* mel_W = (const float*)d_in[26];
    const float* mel_b = (const float*)d_in[27];

    float* ws = (float*)d_ws;
    unsigned* flags = (unsigned*)d_ws;
    float* out = (float*)d_out;
    int T = out_size / (B_ * MEL_);   // 200

    // zero flags + recurrent state
    zero_kernel<<<ZERO_WORDS / 256, 256, 0, stream>>>(ws);

    // embedding
    embed_kernel<<<512, 256, 0, stream>>>(text, emb, ws + OFF_X0);

    // layer0 input projections (bias folded: bih + bhh)
    gemm_f32<<<dim3(32, 16), 256, 0, stream>>>(ws + OFF_X0, 512, Wih00, 512,
                                               bih00, bhh00, ws + OFF_GX0F, 2048, 512);
    gemm_f32<<<dim3(32, 16), 256, 0, stream>>>(ws + OFF_X0, 512, Wih01, 512,
                                               bih01, bhh01, ws + OFF_GX0B, 2048, 512);
    // layer0 recurrence
    lstm_kernel<<<128, 256, 0, stream>>>(ws + OFF_GX0F, ws + OFF_GX0B, Whh00, Whh01,
                                         ws + OFF_H0, ws + OFF_H0S, flags + FLG_L0);
    // decoder weight folds (GX0B dead now)
    wh2_kernel<<<4096, 256, 0, stream>>>(dec_Wih, dec_Whh, mel_W, ws + OFF_WH2);
    bias_kernel<<<8, 256, 0, stream>>>(dec_Wih, dec_bih, dec_bhh, mel_b,
                                       ws + OFF_BA, ws + OFF_BB);
    // layer1 input projections
    gemm_f32<<<dim3(32, 16), 256, 0, stream>>>(ws + OFF_H0, 1024, Wih10, 1024,
                                               bih10, bhh10, ws + OFF_GX1F, 2048, 1024);
    gemm_f32<<<dim3(32, 16), 256, 0, stream>>>(ws + OFF_H0, 1024, Wih11, 1024,
                                               bih11, bhh11, ws + OFF_GX1B, 2048, 1024);
    // layer1 recurrence -> enc
    lstm_kernel<<<128, 256, 0, stream>>>(ws + OFF_GX1F, ws + OFF_GX1B, Whh10, Whh11,
                                         ws + OFF_ENC, ws + OFF_H1S, flags + FLG_L1);
    // enc_part = enc @ W_e^T + attn_b
    gemm_f32<<<dim3(8, 16), 256, 0, stream>>>(ws + OFF_ENC, 1024, attn_W + 512, 1536,
                                              attn_b, nullptr, ws + OFF_ENCP, 512, 1024);
    // WE[b] = Wih_ctx @ ENC_b^T (GX0F dead now)
    we_kernel<<<dim3(2, 32, 8), 256, 0, stream>>>(dec_Wih, ws + OFF_ENC, ws + OFF_WE);
    // decoder: 64 gate WGs + 8 attention WGs, 2 edges/step
    decoder_kernel<<<72, 256, 0, stream>>>(ws, attn_W, attn_v, mel_W, mel_b, out, T,
                                           flags + FLG_DEC);
}

// Round 14
// 9926.961 us; speedup vs baseline: 1.6243x; 1.6243x over previous
//
#include <hip/hip_runtime.h>

// ---------------- problem constants ----------------
#define B_ 8
#define S_ 128
#define H_ 512
#define G_ 2048   // 4H
#define MEL_ 80

// ---------------- ws layout (32-bit word offsets) ----------------
// decoder flags per batch (1024 words): C lines 0..15, A lines 16..31, B line 32
#define FLG_DEC    0                    // 8 * 1024 = 8192
#define FLG_L0     8192                 // 16 groups * 128 words
#define FLG_L1     10240
#define OFF_H0S    12288                // lstm0 h [(dir*8+b)][2][512] = 16384
#define OFF_H1S    28672                // 16384
#define OFF_DH     45056                // dec h [2][b][512] = 8192 (ping-pong)
#define OFF_ATT    53248                // att [b][128] = 1024
#define OFF_HW     54272                // [b][512] = 4096
#define ZERO_WORDS 58368                // = 228*256
#define OFF_X0     58368                        // [bs][512]   524288
#define OFF_GX0F   (OFF_X0 + 524288)            // [bs][2048] 2097152  (-> WE after lstm1)
#define OFF_GX0B   (OFF_GX0F + 2097152)         // (-> WH2 + biases after lstm0)
#define OFF_H0     (OFF_GX0B + 2097152)         // [bs][1024] 1048576
#define OFF_GX1F   (OFF_H0 + 1048576)
#define OFF_GX1B   (OFF_GX1F + 2097152)
#define OFF_ENC    (OFF_GX1B + 2097152)         // [bs][1024] 1048576
#define OFF_ENCP   (OFF_ENC + 1048576)          // [bs][512]   524288
// precomputed regions (reuse dead GX0 buffers)
#define OFF_WE     OFF_GX0F                     // [b][2048][128] = 2097152
#define OFF_WH2    OFF_GX0B                     // [2048][512] = 1048576
#define OFF_BA     (OFF_GX0B + 1048576)         // 2048
#define OFF_BB     (OFF_GX0B + 1050624)         // 2048

// ---------------- helpers ----------------
__device__ __forceinline__ float sigm_f(float x) {
    x = fminf(fmaxf(x, -30.f), 30.f);
    return 1.f / (1.f + __expf(-x));
}
__device__ __forceinline__ float tanh_f(float x) {
    x = fminf(fmaxf(x, -15.f), 15.f);
    float e = __expf(2.f * x);
    return (e - 1.f) / (e + 1.f);
}

// device-scope uncached scalar access (bypasses caches w/o invalidating them)
__device__ __forceinline__ void agw_u(unsigned* p, unsigned v) {
    __hip_atomic_store(p, v, __ATOMIC_RELAXED, __HIP_MEMORY_SCOPE_AGENT);
}
__device__ __forceinline__ unsigned agr_u(const unsigned* p) {
    return __hip_atomic_load(p, __ATOMIC_RELAXED, __HIP_MEMORY_SCOPE_AGENT);
}
__device__ __forceinline__ void agw_f(float* p, float v) {
    agw_u((unsigned*)p, __float_as_uint(v));
}

// device-coherent VECTOR load (sc1): 16B analog of agent-scope atomic load
__device__ __forceinline__ float4 agr_f4(const float* p) {
    float4 v;
    asm volatile("global_load_dwordx4 %0, %1, off sc1\n\t"
                 "s_waitcnt vmcnt(0)"
                 : "=v"(v) : "v"(p) : "memory");
    return v;
}

// ---------------- zero init ----------------
__global__ __launch_bounds__(256) void zero_kernel(float* p) {
    p[blockIdx.x * 256 + threadIdx.x] = 0.f;
}

// ---------------- embedding ----------------
__global__ __launch_bounds__(256) void embed_kernel(const int* __restrict__ text,
                                                    const float* __restrict__ emb,
                                                    float* __restrict__ X) {
    int i = blockIdx.x * 256 + threadIdx.x;
    int bs = i >> 7;
    int h4 = i & 127;
    int ch = text[bs];
    ((float4*)X)[i] = ((const float4*)emb)[ch * 128 + h4];
}

// ---------------- f32 GEMM: C[M,N] = A[M,K] * W[N,K]^T + b1 (+ b2) ----------------
__global__ __launch_bounds__(256) void gemm_f32(const float* __restrict__ A, int lda,
                                                const float* __restrict__ W, int ldw,
                                                const float* __restrict__ b1,
                                                const float* __restrict__ b2,
                                                float* __restrict__ C, int ldc, int K) {
    __shared__ float As[32][68];
    __shared__ float Ws[32][68];
    int tid = threadIdx.x;
    int tx = tid & 15, ty = tid >> 4;
    int n0 = blockIdx.x * 64, m0 = blockIdx.y * 64;
    float acc[4][4] = {};
    int r  = tid >> 3;
    int c4 = (tid & 7) * 4;
    for (int k0 = 0; k0 < K; k0 += 32) {
        float4 a0 = *(const float4*)&A[(m0 + r) * lda + k0 + c4];
        float4 a1 = *(const float4*)&A[(m0 + r + 32) * lda + k0 + c4];
        float4 w0 = *(const float4*)&W[(n0 + r) * ldw + k0 + c4];
        float4 w1 = *(const float4*)&W[(n0 + r + 32) * ldw + k0 + c4];
        As[c4 + 0][r] = a0.x; As[c4 + 1][r] = a0.y; As[c4 + 2][r] = a0.z; As[c4 + 3][r] = a0.w;
        As[c4 + 0][r + 32] = a1.x; As[c4 + 1][r + 32] = a1.y; As[c4 + 2][r + 32] = a1.z; As[c4 + 3][r + 32] = a1.w;
        Ws[c4 + 0][r] = w0.x; Ws[c4 + 1][r] = w0.y; Ws[c4 + 2][r] = w0.z; Ws[c4 + 3][r] = w0.w;
        Ws[c4 + 0][r + 32] = w1.x; Ws[c4 + 1][r + 32] = w1.y; Ws[c4 + 2][r + 32] = w1.z; Ws[c4 + 3][r + 32] = w1.w;
        __syncthreads();
#pragma unroll 8
        for (int kk = 0; kk < 32; ++kk) {
            float4 av = *(const float4*)&As[kk][ty * 4];
            float4 wv = *(const float4*)&Ws[kk][tx * 4];
            acc[0][0] = fmaf(av.x, wv.x, acc[0][0]); acc[0][1] = fmaf(av.x, wv.y, acc[0][1]);
            acc[0][2] = fmaf(av.x, wv.z, acc[0][2]); acc[0][3] = fmaf(av.x, wv.w, acc[0][3]);
            acc[1][0] = fmaf(av.y, wv.x, acc[1][0]); acc[1][1] = fmaf(av.y, wv.y, acc[1][1]);
            acc[1][2] = fmaf(av.y, wv.z, acc[1][2]); acc[1][3] = fmaf(av.y, wv.w, acc[1][3]);
            acc[2][0] = fmaf(av.z, wv.x, acc[2][0]); acc[2][1] = fmaf(av.z, wv.y, acc[2][1]);
            acc[2][2] = fmaf(av.z, wv.z, acc[2][2]); acc[2][3] = fmaf(av.z, wv.w, acc[2][3]);
            acc[3][0] = fmaf(av.w, wv.x, acc[3][0]); acc[3][1] = fmaf(av.w, wv.y, acc[3][1]);
            acc[3][2] = fmaf(av.w, wv.z, acc[3][2]); acc[3][3] = fmaf(av.w, wv.w, acc[3][3]);
        }
        __syncthreads();
    }
#pragma unroll
    for (int i = 0; i < 4; ++i)
#pragma unroll
        for (int j = 0; j < 4; ++j) {
            int n = n0 + tx * 4 + j;
            int m = m0 + ty * 4 + i;
            float bias = (b1 ? b1[n] : 0.f) + (b2 ? b2[n] : 0.f);
            C[m * ldc + n] = acc[i][j] + bias;
        }
}

// ---------------- WE[b][r][s] = Wih_ctx[r] . ENC_b[s]  (K=1024) ----------------
__global__ __launch_bounds__(256) void we_kernel(const float* __restrict__ Wih,
                                                 const float* __restrict__ ENC,
                                                 float* __restrict__ WE) {
    const float* A = Wih + 80;                          // [2048][1024], lda 1104
    const float* W = ENC + (size_t)blockIdx.z * 131072; // [128][1024]
    float* C = WE + (size_t)blockIdx.z * 262144;        // [2048][128]
    __shared__ float As[32][68];
    __shared__ float Ws[32][68];
    int tid = threadIdx.x;
    int tx = tid & 15, ty = tid >> 4;
    int n0 = blockIdx.x * 64, m0 = blockIdx.y * 64;
    float acc[4][4] = {};
    int r  = tid >> 3;
    int c4 = (tid & 7) * 4;
    for (int k0 = 0; k0 < 1024; k0 += 32) {
        float4 a0 = *(const float4*)&A[(size_t)(m0 + r) * 1104 + k0 + c4];
        float4 a1 = *(const float4*)&A[(size_t)(m0 + r + 32) * 1104 + k0 + c4];
        float4 w0 = *(const float4*)&W[(n0 + r) * 1024 + k0 + c4];
        float4 w1 = *(const float4*)&W[(n0 + r + 32) * 1024 + k0 + c4];
        As[c4 + 0][r] = a0.x; As[c4 + 1][r] = a0.y; As[c4 + 2][r] = a0.z; As[c4 + 3][r] = a0.w;
        As[c4 + 0][r + 32] = a1.x; As[c4 + 1][r + 32] = a1.y; As[c4 + 2][r + 32] = a1.z; As[c4 + 3][r + 32] = a1.w;
        Ws[c4 + 0][r] = w0.x; Ws[c4 + 1][r] = w0.y; Ws[c4 + 2][r] = w0.z; Ws[c4 + 3][r] = w0.w;
        Ws[c4 + 0][r + 32] = w1.x; Ws[c4 + 1][r + 32] = w1.y; Ws[c4 + 2][r + 32] = w1.z; Ws[c4 + 3][r + 32] = w1.w;
        __syncthreads();
#pragma unroll 8
        for (int kk = 0; kk < 32; ++kk) {
            float4 av = *(const float4*)&As[kk][ty * 4];
            float4 wv = *(const float4*)&Ws[kk][tx * 4];
            acc[0][0] = fmaf(av.x, wv.x, acc[0][0]); acc[0][1] = fmaf(av.x, wv.y, acc[0][1]);
            acc[0][2] = fmaf(av.x, wv.z, acc[0][2]); acc[0][3] = fmaf(av.x, wv.w, acc[0][3]);
            acc[1][0] = fmaf(av.y, wv.x, acc[1][0]); acc[1][1] = fmaf(av.y, wv.y, acc[1][1]);
            acc[1][2] = fmaf(av.y, wv.z, acc[1][2]); acc[1][3] = fmaf(av.y, wv.w, acc[1][3]);
            acc[2][0] = fmaf(av.z, wv.x, acc[2][0]); acc[2][1] = fmaf(av.z, wv.y, acc[2][1]);
            acc[2][2] = fmaf(av.z, wv.z, acc[2][2]); acc[2][3] = fmaf(av.z, wv.w, acc[2][3]);
            acc[3][0] = fmaf(av.w, wv.x, acc[3][0]); acc[3][1] = fmaf(av.w, wv.y, acc[3][1]);
            acc[3][2] = fmaf(av.w, wv.z, acc[3][2]); acc[3][3] = fmaf(av.w, wv.w, acc[3][3]);
        }
        __syncthreads();
    }
#pragma unroll
    for (int i = 0; i < 4; ++i)
#pragma unroll
        for (int j = 0; j < 4; ++j)
            C[(size_t)(m0 + ty * 4 + i) * 128 + n0 + tx * 4 + j] = acc[i][j];
}

// ---------------- WH2 = dec_Whh + Wih[:,:80] @ mel_W ----------------
__global__ __launch_bounds__(256) void wh2_kernel(const float* __restrict__ Wih,
                                                  const float* __restrict__ Whh,
                                                  const float* __restrict__ melW,
                                                  float* __restrict__ WH2) {
    int wg = blockIdx.x;
    int tid = threadIdx.x;
    int r = wg >> 1;
    int k = (wg & 1) * 256 + tid;
    __shared__ float wrow[80];
    if (tid < 80) wrow[tid] = Wih[(size_t)r * 1104 + tid];
    __syncthreads();
    float acc = Whh[(size_t)r * 512 + k];
#pragma unroll 8
    for (int m = 0; m < 80; ++m)
        acc = fmaf(wrow[m], melW[m * 512 + k], acc);
    WH2[(size_t)r * 512 + k] = acc;
}

// ---------------- biasA = bih+bhh ; biasB = biasA + Wih[:,:80].mel_b ----------------
__global__ __launch_bounds__(256) void bias_kernel(const float* __restrict__ Wih,
                                                   const float* __restrict__ bih,
                                                   const float* __restrict__ bhh,
                                                   const float* __restrict__ melb,
                                                   float* __restrict__ BA,
                                                   float* __restrict__ BB) {
    int r = blockIdx.x * 256 + threadIdx.x;
    float a = bih[r] + bhh[r];
    float b2 = 0.f;
#pragma unroll 8
    for (int m = 0; m < 80; ++m)
        b2 = fmaf(Wih[(size_t)r * 1104 + m], melb[m], b2);
    BA[r] = a;
    BB[r] = a + b2;
}

// ---------------- per-(dir,batch) LSTM: slice-major (r12) + pipelined poll + fast flag
__global__ __launch_bounds__(256) void lstm_kernel(const float* __restrict__ GXf,
                                                   const float* __restrict__ GXb,
                                                   const float* __restrict__ Whh_f,
                                                   const float* __restrict__ Whh_b,
                                                   float* __restrict__ Hout,
                                                   float* __restrict__ hstate,
                                                   unsigned* __restrict__ flagsL) {
    int wg  = blockIdx.x;
    int s   = wg & 7;
    int g16 = wg >> 3;
    int dir = g16 >> 3;
    int b   = g16 & 7;
    const float* GX  = dir ? GXb : GXf;
    const float* Whh = dir ? Whh_b : Whh_f;
    float* hs = hstate + g16 * 1024;         // [2][512]
    unsigned* fg = flagsL + g16 * 128;       // 8 flag lines

    int tid = threadIdx.x;
    int g = tid >> 6, c = tid & 63;
    int grow = g * 512 + s * 64 + c;
    const float* wr = Whh + (size_t)grow * 512;

    __shared__ float hsh[512];
    __shared__ float gvL[4][64];

    float cst = 0.f;

    for (int t = 0; t < 128; ++t) {
        // pipelined poll+stage: lane waits only on its own producer (slice tid>>4)
        if (tid < 128) {
            const unsigned* f = fg + (tid >> 4) * 16;
            while (agr_u(f) < (unsigned)t)
                __builtin_amdgcn_s_sleep(1);
            *(float4*)&hsh[tid * 4] = agr_f4(hs + (t & 1) * 512 + tid * 4);
        }
        __syncthreads();

        int st = dir ? (127 - t) : t;
        float acc = GX[((size_t)b * S_ + st) * G_ + grow];
        float a0 = 0.f, a1 = 0.f, a2 = 0.f, a3 = 0.f;
#pragma unroll 8
        for (int k = 0; k < 512; k += 4) {
            float4 wv = *(const float4*)(wr + k);
            float4 hv = *(const float4*)&hsh[k];
            a0 = fmaf(wv.x, hv.x, a0); a1 = fmaf(wv.y, hv.y, a1);
            a2 = fmaf(wv.z, hv.z, a2); a3 = fmaf(wv.w, hv.w, a3);
        }
        gvL[g][c] = acc + (a0 + a1) + (a2 + a3);
        __syncthreads();

        // fast flag: wave 0 writes h, drains its own stores, sets flag (no barrier)
        if (tid < 64) {
            float gi = gvL[0][tid], gf = gvL[1][tid];
            float gg = gvL[2][tid], go = gvL[3][tid];
            float c2 = sigm_f(gf) * cst + sigm_f(gi) * tanh_f(gg);
            float h2 = sigm_f(go) * tanh_f(c2);
            cst = c2;
            agw_f(hs + ((t & 1) ^ 1) * 512 + s * 64 + tid, h2);
            asm volatile("s_waitcnt vmcnt(0)" ::: "memory");
            if (tid == 0)
                agw_u(fg + s * 16, (unsigned)(t + 1));
            Hout[((size_t)b * S_ + st) * 1024 + dir * 512 + s * 64 + tid] = h2;
        }
    }
}

// ---------------- decoder: folded gates (r12 structure), 136 WGs ----------------
// gate WG: wg = b*16+s -> XCD s%8: slice s = cols [s*32,(s+1)*32) x 4 gates,
// streams WH2 slice + WE slice (L2-hot); also computes hW rows [s*32,(s+1)*32).
// attn WG: wg = 128+b -> XCD b: scores+softmax -> att; mel off-path -> out.
// 3 edges/step: fC (16 slices: h ready) -> fA (16: hW ready) -> fB (att ready).
// This round: per-lane pipelined polls (slice = tid>>3) + wave0 fast flags.
__global__ __launch_bounds__(256) void decoder_kernel(float* __restrict__ ws,
                                                      const float* __restrict__ attn_W,
                                                      const float* __restrict__ attn_v,
                                                      const float* __restrict__ mel_W,
                                                      const float* __restrict__ mel_b,
                                                      float* __restrict__ out, int T,
                                                      unsigned* __restrict__ flags) {
    float* ENCP = ws + OFF_ENCP;
    float* DH   = ws + OFF_DH;    // [2][8][512]
    float* ATT  = ws + OFF_ATT;   // [8][128]
    float* HW   = ws + OFF_HW;    // [8][512]
    const float* WE  = ws + OFF_WE;
    const float* WH2 = ws + OFF_WH2;
    const float* BA  = ws + OFF_BA;
    const float* BB  = ws + OFF_BB;

    int wg  = blockIdx.x;
    int tid = threadIdx.x;

    if (wg < 128) {
        // ================= gate WG (slice s, batch b) =================
        int s = wg & 15;
        int b = wg >> 4;
        unsigned* fC = flags + b * 1024;
        unsigned* fA = fC + 16 * 16;
        unsigned* fB = fC + 32 * 16;

        int r   = tid >> 1;                 // local row 0..127
        int half = tid & 1;
        int grow = (r >> 5) * 512 + s * 32 + (r & 31);
        const float* wh2_half = WH2 + (size_t)grow * 512 + half * 256;
        const float* we_row   = WE + ((size_t)b * 2048 + grow) * 128 + half * 64;
        float bias_a = (half == 0) ? BA[grow] : 0.f;
        float bias_b = (half == 0) ? BB[grow] : 0.f;
        // hW mapping (conflict-free broadcast): r2 = tid&31, oct = tid>>5
        int r2 = tid & 31, oct = tid >> 5;
        const float* wh_row = attn_W + (size_t)(s * 32 + r2) * 1536 + oct * 64;

        __shared__ float hsh[512];
        __shared__ float hwred[32][9];
        __shared__ float gBx[128][2];
        __shared__ float gv[128];
        __shared__ float attL[128];

        float cst = 0.f;   // tid<32: col = s*32+tid

        for (int t = 0; t < T; ++t) {
            // ---- stage h_t: per-lane poll (slice tid>>3) + vector stage ----
            if (tid < 128) {
                const unsigned* f = fC + (tid >> 3) * 16;
                while (agr_u(f) < (unsigned)t)
                    __builtin_amdgcn_s_sleep(1);
                *(float4*)&hsh[tid * 4] = agr_f4(DH + (t & 1) * 4096 + b * 512 + tid * 4);
            }
            __syncthreads();

            // hW slice (broadcast LDS reads)
            {
                const float* hp = hsh + oct * 64;
                float w = 0.f;
#pragma unroll 8
                for (int k = 0; k < 64; k += 4) {
                    float4 wv = *(const float4*)(wh_row + k);
                    float4 hv = *(const float4*)(hp + k);
                    w = fmaf(wv.x, hv.x, w); w = fmaf(wv.y, hv.y, w);
                    w = fmaf(wv.z, hv.z, w); w = fmaf(wv.w, hv.w, w);
                }
                hwred[r2][oct] = w;
            }
            __syncthreads();
            // fast flag: wave 0 writes HW slice, drains, sets fA (no barrier)
            if (tid < 32) {
                float hw = hwred[tid][0] + hwred[tid][1] + hwred[tid][2] + hwred[tid][3]
                         + hwred[tid][4] + hwred[tid][5] + hwred[tid][6] + hwred[tid][7];
                agw_f(HW + b * 512 + s * 32 + tid, hw);
                asm volatile("s_waitcnt vmcnt(0)" ::: "memory");
                if (tid == 0)
                    agw_u(fA + s * 16, (unsigned)(t + 1));
            }

            // WH2.h partial (overlaps attention phase; stays in register)
            float wpart = (t == 0) ? bias_a : bias_b;
            {
                const float* hp = hsh + half * 256;
                float a0 = 0.f, a1 = 0.f, a2 = 0.f, a3 = 0.f;
#pragma unroll 8
                for (int k = 0; k < 256; k += 4) {
                    float4 wv = *(const float4*)(wh2_half + k);
                    float4 hv = *(const float4*)(hp + k);
                    a0 = fmaf(wv.x, hv.x, a0); a1 = fmaf(wv.y, hv.y, a1);
                    a2 = fmaf(wv.z, hv.z, a2); a3 = fmaf(wv.w, hv.w, a3);
                }
                wpart += (a0 + a1) + (a2 + a3);
            }

            // ---- stage att: wave-0 poll (single flag) + stage ----
            if (tid < 32) {
                while (agr_u(fB) < (unsigned)(t + 1))
                    __builtin_amdgcn_s_sleep(1);
                *(float4*)&attL[tid * 4] = agr_f4(ATT + b * 128 + tid * 4);
            }
            __syncthreads();

            // WE.att (K=64 per half)
            {
                const float* ap = attL + half * 64;
                float a0 = 0.f, a1 = 0.f, a2 = 0.f, a3 = 0.f;
#pragma unroll 8
                for (int k = 0; k < 64; k += 4) {
                    float4 wv = *(const float4*)(we_row + k);
                    a0 = fmaf(wv.x, ap[k + 0], a0); a1 = fmaf(wv.y, ap[k + 1], a1);
                    a2 = fmaf(wv.z, ap[k + 2], a2); a3 = fmaf(wv.w, ap[k + 3], a3);
                }
                gBx[r][half] = wpart + (a0 + a1) + (a2 + a3);
            }
            __syncthreads();
            if (tid < 128)
                gv[tid] = gBx[tid][0] + gBx[tid][1];
            __syncthreads();
            // cell + fast flag (wave 0)
            if (tid < 32) {
                float gi = gv[tid], gf = gv[32 + tid], gg = gv[64 + tid], go = gv[96 + tid];
                float c2 = sigm_f(gf) * cst + sigm_f(gi) * tanh_f(gg);
                float h2 = sigm_f(go) * tanh_f(c2);
                cst = c2;
                agw_f(DH + ((t + 1) & 1) * 4096 + b * 512 + s * 32 + tid, h2);
                asm volatile("s_waitcnt vmcnt(0)" ::: "memory");
                if (tid == 0)
                    agw_u(fC + s * 16, (unsigned)(t + 1));
            }
        }
    } else {
        // ================= attention WG (batch b) =================
        int b = wg - 128;
        unsigned* fC = flags + b * 1024;
        unsigned* fA = fC + 16 * 16;
        unsigned* fB = fC + 32 * 16;

        __shared__ float hw2[512];
        __shared__ float dh2[512];
        __shared__ float scred[128][2];
        __shared__ float red[128];
        __shared__ float att[128];
        __shared__ float melp[80][2];

        int r = tid >> 1, half = tid & 1;

        for (int t = 0; t < T; ++t) {
            // stage hW (per-lane poll, slice tid>>3)
            if (tid < 128) {
                const unsigned* f = fA + (tid >> 3) * 16;
                while (agr_u(f) < (unsigned)(t + 1))
                    __builtin_amdgcn_s_sleep(1);
                *(float4*)&hw2[tid * 4] = agr_f4(HW + b * 512 + tid * 4);
            }
            __syncthreads();

            // scores: sI = tid&127, k-half = tid>>7
            {
                int sI = tid & 127, kh = tid >> 7;
                const float* ep = ENCP + ((size_t)b * S_ + sI) * 512 + kh * 256;
                const float* hp = hw2 + kh * 256;
                const float* vv = attn_v + kh * 256;
                float a0 = 0.f, a1 = 0.f, a2 = 0.f, a3 = 0.f;
#pragma unroll 4
                for (int k = 0; k < 256; k += 4) {
                    float4 e4 = *(const float4*)(ep + k);
                    float4 h4 = *(const float4*)(hp + k);
                    float4 v4 = *(const float4*)(vv + k);
                    a0 = fmaf(tanh_f(e4.x + h4.x), v4.x, a0);
                    a1 = fmaf(tanh_f(e4.y + h4.y), v4.y, a1);
                    a2 = fmaf(tanh_f(e4.z + h4.z), v4.z, a2);
                    a3 = fmaf(tanh_f(e4.w + h4.w), v4.w, a3);
                }
                scred[sI][kh] = (a0 + a1) + (a2 + a3);
            }
            __syncthreads();

            float sc = 0.f;
            if (tid < 128) {
                sc = scred[tid][0] + scred[tid][1];
                red[tid] = sc;
            }
            __syncthreads();
            for (int off = 64; off >= 1; off >>= 1) {
                if (tid < off) red[tid] = fmaxf(red[tid], red[tid + off]);
                __syncthreads();
            }
            float mx = red[0];
            __syncthreads();
            if (tid < 128) {
                float e = __expf(sc - mx);
                att[tid] = e;
                red[tid] = e;
            }
            __syncthreads();
            if (tid < 64) red[tid] += red[tid + 64];
            __syncthreads();
            for (int off = 32; off >= 1; off >>= 1) {
                if (tid < off) red[tid] += red[tid + off];
                __syncthreads();
            }
            float inv = 1.f / red[0];

            // att write + fast flag (wave 0: lanes 0..31 store 4 each)
            if (tid < 32) {
                agw_f(ATT + b * 128 + tid * 4 + 0, att[tid * 4 + 0] * inv);
                agw_f(ATT + b * 128 + tid * 4 + 1, att[tid * 4 + 1] * inv);
                agw_f(ATT + b * 128 + tid * 4 + 2, att[tid * 4 + 2] * inv);
                agw_f(ATT + b * 128 + tid * 4 + 3, att[tid * 4 + 3] * inv);
                asm volatile("s_waitcnt vmcnt(0)" ::: "memory");
                if (tid == 0)
                    agw_u(fB, (unsigned)(t + 1));
            }

            // ---- off-critical-path: mel from h_t -> out[t-1] ----
            if (t > 0) {
                if (tid < 128) {
                    const unsigned* f = fC + (tid >> 3) * 16;
                    while (agr_u(f) < (unsigned)t)
                        __builtin_amdgcn_s_sleep(1);
                    *(float4*)&dh2[tid * 4] = agr_f4(DH + (t & 1) * 4096 + b * 512 + tid * 4);
                }
                __syncthreads();
                if (tid < 160) {
                    const float* wp = mel_W + (size_t)r * 512 + half * 256;
                    const float* hp = dh2 + half * 256;
                    float a0 = 0.f, a1 = 0.f, a2 = 0.f, a3 = 0.f;
#pragma unroll 8
                    for (int k = 0; k < 256; k += 4) {
                        float4 wv = *(const float4*)(wp + k);
                        float4 hv = *(const float4*)(hp + k);
                        a0 = fmaf(wv.x, hv.x, a0); a1 = fmaf(wv.y, hv.y, a1);
                        a2 = fmaf(wv.z, hv.z, a2); a3 = fmaf(wv.w, hv.w, a3);
                    }
                    melp[r][half] = (a0 + a1) + (a2 + a3);
                }
                __syncthreads();
                if (tid < 80)
                    out[b * MEL_ * T + tid * T + (t - 1)] = melp[tid][0] + melp[tid][1] + mel_b[tid];
            }
        }

        // epilogue: final mel from h_T -> out[T-1]
        if (tid < 128) {
            const unsigned* f = fC + (tid >> 3) * 16;
            while (agr_u(f) < (unsigned)T)
                __builtin_amdgcn_s_sleep(1);
            *(float4*)&dh2[tid * 4] = agr_f4(DH + (T & 1) * 4096 + b * 512 + tid * 4);
        }
        __syncthreads();
        if (tid < 160) {
            const float* wp = mel_W + (size_t)r * 512 + half * 256;
            const float* hp = dh2 + half * 256;
            float a0 = 0.f, a1 = 0.f, a2 = 0.f, a3 = 0.f;
#pragma unroll 8
            for (int k = 0; k < 256; k += 4) {
                float4 wv = *(const float4*)(wp + k);
                float4 hv = *(const float4*)(hp + k);
                a0 = fmaf(wv.x, hv.x, a0); a1 = fmaf(wv.y, hv.y, a1);
                a2 = fmaf(wv.z, hv.z, a2); a3 = fmaf(wv.w, hv.w, a3);
            }
            melp[r][half] = (a0 + a1) + (a2 + a3);
        }
        __syncthreads();
        if (tid < 80)
            out[b * MEL_ * T + tid * T + (T - 1)] = melp[tid][0] + melp[tid][1] + mel_b[tid];
    }
}

// ---------------- host launch ----------------
extern "C" void kernel_launch(void* const* d_in, const int* in_sizes, int n_in,
                              void* d_out, int out_size, void* d_ws, size_t ws_size,
                              hipStream_t stream) {
    const int*   text  = (const int*)d_in[0];
    const float* emb   = (const float*)d_in[2];
    const float* Wih00 = (const float*)d_in[3];
    const float* Whh00 = (const float*)d_in[4];
    const float* bih00 = (const float*)d_in[5];
    const float* bhh00 = (const float*)d_in[6];
    const float* Wih01 = (const float*)d_in[7];
    const float* Whh01 = (const float*)d_in[8];
    const float* bih01 = (const float*)d_in[9];
    const float* bhh01 = (const float*)d_in[10];
    const float* Wih10 = (const float*)d_in[11];
    const float* Whh10 = (const float*)d_in[12];
    const float* bih10 = (const float*)d_in[13];
    const float* bhh10 = (const float*)d_in[14];
    const float* Wih11 = (const float*)d_in[15];
    const float* Whh11 = (const float*)d_in[16];
    const float* bih11 = (const float*)d_in[17];
    const float* bhh11 = (const float*)d_in[18];
    const float* attn_W = (const float*)d_in[19];
    const float* attn_b = (const float*)d_in[20];
    const float* attn_v = (const float*)d_in[21];
    const float* dec_Wih = (const float*)d_in[22];
    const float* dec_Whh = (const float*)d_in[23];
    const float* dec_bih = (const float*)d_in[24];
    const float* dec_bhh = (const float*)d_in[25];
    const float* mel_W = (const float*)d_in[26];
    const float* mel_b = (const float*)d_in[27];

    float* ws = (float*)d_ws;
    unsigned* flags = (unsigned*)d_ws;
    float* out = (float*)d_out;
    int T = out_size / (B_ * MEL_);   // 200

    // zero flags + recurrent state
    zero_kernel<<<ZERO_WORDS / 256, 256, 0, stream>>>(ws);

    // embedding
    embed_kernel<<<512, 256, 0, stream>>>(text, emb, ws + OFF_X0);

    // layer0 input projections (bias folded: bih + bhh)
    gemm_f32<<<dim3(32, 16), 256, 0, stream>>>(ws + OFF_X0, 512, Wih00, 512,
                                               bih00, bhh00, ws + OFF_GX0F, 2048, 512);
    gemm_f32<<<dim3(32, 16), 256, 0, stream>>>(ws + OFF_X0, 512, Wih01, 512,
                                               bih01, bhh01, ws + OFF_GX0B, 2048, 512);
    // layer0 recurrence
    lstm_kernel<<<128, 256, 0, stream>>>(ws + OFF_GX0F, ws + OFF_GX0B, Whh00, Whh01,
                                         ws + OFF_H0, ws + OFF_H0S, flags + FLG_L0);
    // decoder weight folds (GX0B dead now)
    wh2_kernel<<<4096, 256, 0, stream>>>(dec_Wih, dec_Whh, mel_W, ws + OFF_WH2);
    bias_kernel<<<8, 256, 0, stream>>>(dec_Wih, dec_bih, dec_bhh, mel_b,
                                       ws + OFF_BA, ws + OFF_BB);
    // layer1 input projections
    gemm_f32<<<dim3(32, 16), 256, 0, stream>>>(ws + OFF_H0, 1024, Wih10, 1024,
                                               bih10, bhh10, ws + OFF_GX1F, 2048, 1024);
    gemm_f32<<<dim3(32, 16), 256, 0, stream>>>(ws + OFF_H0, 1024, Wih11, 1024,
                                               bih11, bhh11, ws + OFF_GX1B, 2048, 1024);
    // layer1 recurrence -> enc
    lstm_kernel<<<128, 256, 0, stream>>>(ws + OFF_GX1F, ws + OFF_GX1B, Whh10, Whh11,
                                         ws + OFF_ENC, ws + OFF_H1S, flags + FLG_L1);
    // enc_part = enc @ W_e^T + attn_b
    gemm_f32<<<dim3(8, 16), 256, 0, stream>>>(ws + OFF_ENC, 1024, attn_W + 512, 1536,
                                              attn_b, nullptr, ws + OFF_ENCP, 512, 1024);
    // WE[b] = Wih_ctx @ ENC_b^T (GX0F dead now)
    we_kernel<<<dim3(2, 32, 8), 256, 0, stream>>>(dec_Wih, ws + OFF_ENC, ws + OFF_WE);
    // decoder: r12 structure + pipelined polls + fast flags
    decoder_kernel<<<136, 256, 0, stream>>>(ws, attn_W, attn_v, mel_W, mel_b, out, T,
                                            flags + FLG_DEC);
}

// Round 16
// 9902.005 us; speedup vs baseline: 1.6284x; 1.0025x over previous
//
#include <hip/hip_runtime.h>

// ---------------- problem constants ----------------
#define B_ 8
#define S_ 128
#define H_ 512
#define G_ 2048   // 4H
#define MEL_ 80

// ---------------- ws layout (32-bit word offsets) ----------------
// decoder flags per batch (1024 words): fCh lines 0..15, fCp lines 16..31, fB line 32
#define FLG_DEC    0                    // 8 * 1024 = 8192
#define FLG_L0     8192                 // 16 groups * 128 words
#define FLG_L1     10240
#define OFF_H0S    12288                // lstm0 h [(dir*8+b)][2][512] = 16384
#define OFF_H1S    28672                // 16384
#define OFF_DH     45056                // dec h [2][b][512] = 8192 (ping-pong)
#define OFF_ATT    53248                // att [b][128] = 1024
#define OFF_HW     54272                // (unused) 4096
#define ZERO_WORDS 58368                // = 228*256
#define OFF_X0     58368                        // [bs][512]   524288
#define OFF_GX0F   (OFF_X0 + 524288)            // [bs][2048] 2097152  (-> WE)
#define OFF_GX0B   (OFF_GX0F + 2097152)         // (-> WH2 + biases)
#define OFF_H0     (OFF_GX0B + 2097152)         // [bs][1024] 1048576
#define OFF_GX1F   (OFF_H0 + 1048576)           // (-> HWP after lstm1)
#define OFF_GX1B   (OFF_GX1F + 2097152)
#define OFF_ENC    (OFF_GX1B + 2097152)         // [bs][1024] 1048576
#define OFF_ENCP   (OFF_ENC + 1048576)          // [bs][512]   524288
// precomputed regions (reuse dead buffers)
#define OFF_WE     OFF_GX0F                     // [b][2048][128] = 2097152
#define OFF_WH2    OFF_GX0B                     // [2048][512] = 1048576
#define OFF_BA     (OFF_GX0B + 1048576)         // 2048
#define OFF_BB     (OFF_GX0B + 1050624)         // 2048
#define OFF_HWP    OFF_GX1F                     // [b][16][512] = 65536 (zeroed post-lstm1)

// ---------------- helpers ----------------
__device__ __forceinline__ float sigm_f(float x) {
    x = fminf(fmaxf(x, -30.f), 30.f);
    return 1.f / (1.f + __expf(-x));
}
__device__ __forceinline__ float tanh_f(float x) {
    x = fminf(fmaxf(x, -15.f), 15.f);
    float e = __expf(2.f * x);
    return (e - 1.f) / (e + 1.f);
}

// device-scope uncached scalar access (bypasses caches w/o invalidating them)
__device__ __forceinline__ void agw_u(unsigned* p, unsigned v) {
    __hip_atomic_store(p, v, __ATOMIC_RELAXED, __HIP_MEMORY_SCOPE_AGENT);
}
__device__ __forceinline__ unsigned agr_u(const unsigned* p) {
    return __hip_atomic_load(p, __ATOMIC_RELAXED, __HIP_MEMORY_SCOPE_AGENT);
}
__device__ __forceinline__ void agw_f(float* p, float v) {
    agw_u((unsigned*)p, __float_as_uint(v));
}

// device-coherent VECTOR load (sc1)
__device__ __forceinline__ float4 agr_f4(const float* p) {
    float4 v;
    asm volatile("global_load_dwordx4 %0, %1, off sc1\n\t"
                 "s_waitcnt vmcnt(0)"
                 : "=v"(v) : "v"(p) : "memory");
    return v;
}
// coherent 4-scalar store + ONE drain (float4 asm INPUTS unsupported -> scalar stores)
__device__ __forceinline__ void agw_f4(float* p, float4 v) {
    agw_f(p + 0, v.x); agw_f(p + 1, v.y); agw_f(p + 2, v.z); agw_f(p + 3, v.w);
    asm volatile("s_waitcnt vmcnt(0)" ::: "memory");
}
// batched: 4 coherent loads, ONE drain (early-clobber outputs)
__device__ __forceinline__ void agr_f4x4(const float* p0, const float* p1,
                                         const float* p2, const float* p3,
                                         float4& a, float4& b, float4& c, float4& d) {
    asm volatile("global_load_dwordx4 %0, %4, off sc1\n\t"
                 "global_load_dwordx4 %1, %5, off sc1\n\t"
                 "global_load_dwordx4 %2, %6, off sc1\n\t"
                 "global_load_dwordx4 %3, %7, off sc1\n\t"
                 "s_waitcnt vmcnt(0)"
                 : "=&v"(a), "=&v"(b), "=&v"(c), "=&v"(d)
                 : "v"(p0), "v"(p1), "v"(p2), "v"(p3) : "memory");
}

// ---------------- zero init ----------------
__global__ __launch_bounds__(256) void zero_kernel(float* p) {
    p[blockIdx.x * 256 + threadIdx.x] = 0.f;
}

// ---------------- embedding ----------------
__global__ __launch_bounds__(256) void embed_kernel(const int* __restrict__ text,
                                                    const float* __restrict__ emb,
                                                    float* __restrict__ X) {
    int i = blockIdx.x * 256 + threadIdx.x;
    int bs = i >> 7;
    int h4 = i & 127;
    int ch = text[bs];
    ((float4*)X)[i] = ((const float4*)emb)[ch * 128 + h4];
}

// ---------------- f32 GEMM: C[M,N] = A[M,K] * W[N,K]^T + b1 (+ b2) ----------------
__global__ __launch_bounds__(256) void gemm_f32(const float* __restrict__ A, int lda,
                                                const float* __restrict__ W, int ldw,
                                                const float* __restrict__ b1,
                                                const float* __restrict__ b2,
                                                float* __restrict__ C, int ldc, int K) {
    __shared__ float As[32][68];
    __shared__ float Ws[32][68];
    int tid = threadIdx.x;
    int tx = tid & 15, ty = tid >> 4;
    int n0 = blockIdx.x * 64, m0 = blockIdx.y * 64;
    float acc[4][4] = {};
    int r  = tid >> 3;
    int c4 = (tid & 7) * 4;
    for (int k0 = 0; k0 < K; k0 += 32) {
        float4 a0 = *(const float4*)&A[(m0 + r) * lda + k0 + c4];
        float4 a1 = *(const float4*)&A[(m0 + r + 32) * lda + k0 + c4];
        float4 w0 = *(const float4*)&W[(n0 + r) * ldw + k0 + c4];
        float4 w1 = *(const float4*)&W[(n0 + r + 32) * ldw + k0 + c4];
        As[c4 + 0][r] = a0.x; As[c4 + 1][r] = a0.y; As[c4 + 2][r] = a0.z; As[c4 + 3][r] = a0.w;
        As[c4 + 0][r + 32] = a1.x; As[c4 + 1][r + 32] = a1.y; As[c4 + 2][r + 32] = a1.z; As[c4 + 3][r + 32] = a1.w;
        Ws[c4 + 0][r] = w0.x; Ws[c4 + 1][r] = w0.y; Ws[c4 + 2][r] = w0.z; Ws[c4 + 3][r] = w0.w;
        Ws[c4 + 0][r + 32] = w1.x; Ws[c4 + 1][r + 32] = w1.y; Ws[c4 + 2][r + 32] = w1.z; Ws[c4 + 3][r + 32] = w1.w;
        __syncthreads();
#pragma unroll 8
        for (int kk = 0; kk < 32; ++kk) {
            float4 av = *(const float4*)&As[kk][ty * 4];
            float4 wv = *(const float4*)&Ws[kk][tx * 4];
            acc[0][0] = fmaf(av.x, wv.x, acc[0][0]); acc[0][1] = fmaf(av.x, wv.y, acc[0][1]);
            acc[0][2] = fmaf(av.x, wv.z, acc[0][2]); acc[0][3] = fmaf(av.x, wv.w, acc[0][3]);
            acc[1][0] = fmaf(av.y, wv.x, acc[1][0]); acc[1][1] = fmaf(av.y, wv.y, acc[1][1]);
            acc[1][2] = fmaf(av.y, wv.z, acc[1][2]); acc[1][3] = fmaf(av.y, wv.w, acc[1][3]);
            acc[2][0] = fmaf(av.z, wv.x, acc[2][0]); acc[2][1] = fmaf(av.z, wv.y, acc[2][1]);
            acc[2][2] = fmaf(av.z, wv.z, acc[2][2]); acc[2][3] = fmaf(av.z, wv.w, acc[2][3]);
            acc[3][0] = fmaf(av.w, wv.x, acc[3][0]); acc[3][1] = fmaf(av.w, wv.y, acc[3][1]);
            acc[3][2] = fmaf(av.w, wv.z, acc[3][2]); acc[3][3] = fmaf(av.w, wv.w, acc[3][3]);
        }
        __syncthreads();
    }
#pragma unroll
    for (int i = 0; i < 4; ++i)
#pragma unroll
        for (int j = 0; j < 4; ++j) {
            int n = n0 + tx * 4 + j;
            int m = m0 + ty * 4 + i;
            float bias = (b1 ? b1[n] : 0.f) + (b2 ? b2[n] : 0.f);
            C[m * ldc + n] = acc[i][j] + bias;
        }
}

// ---------------- WE[b][r][s] = Wih_ctx[r] . ENC_b[s]  (K=1024) ----------------
__global__ __launch_bounds__(256) void we_kernel(const float* __restrict__ Wih,
                                                 const float* __restrict__ ENC,
                                                 float* __restrict__ WE) {
    const float* A = Wih + 80;
    const float* W = ENC + (size_t)blockIdx.z * 131072;
    float* C = WE + (size_t)blockIdx.z * 262144;
    __shared__ float As[32][68];
    __shared__ float Ws[32][68];
    int tid = threadIdx.x;
    int tx = tid & 15, ty = tid >> 4;
    int n0 = blockIdx.x * 64, m0 = blockIdx.y * 64;
    float acc[4][4] = {};
    int r  = tid >> 3;
    int c4 = (tid & 7) * 4;
    for (int k0 = 0; k0 < 1024; k0 += 32) {
        float4 a0 = *(const float4*)&A[(size_t)(m0 + r) * 1104 + k0 + c4];
        float4 a1 = *(const float4*)&A[(size_t)(m0 + r + 32) * 1104 + k0 + c4];
        float4 w0 = *(const float4*)&W[(n0 + r) * 1024 + k0 + c4];
        float4 w1 = *(const float4*)&W[(n0 + r + 32) * 1024 + k0 + c4];
        As[c4 + 0][r] = a0.x; As[c4 + 1][r] = a0.y; As[c4 + 2][r] = a0.z; As[c4 + 3][r] = a0.w;
        As[c4 + 0][r + 32] = a1.x; As[c4 + 1][r + 32] = a1.y; As[c4 + 2][r + 32] = a1.z; As[c4 + 3][r + 32] = a1.w;
        Ws[c4 + 0][r] = w0.x; Ws[c4 + 1][r] = w0.y; Ws[c4 + 2][r] = w0.z; Ws[c4 + 3][r] = w0.w;
        Ws[c4 + 0][r + 32] = w1.x; Ws[c4 + 1][r + 32] = w1.y; Ws[c4 + 2][r + 32] = w1.z; Ws[c4 + 3][r + 32] = w1.w;
        __syncthreads();
#pragma unroll 8
        for (int kk = 0; kk < 32; ++kk) {
            float4 av = *(const float4*)&As[kk][ty * 4];
            float4 wv = *(const float4*)&Ws[kk][tx * 4];
            acc[0][0] = fmaf(av.x, wv.x, acc[0][0]); acc[0][1] = fmaf(av.x, wv.y, acc[0][1]);
            acc[0][2] = fmaf(av.x, wv.z, acc[0][2]); acc[0][3] = fmaf(av.x, wv.w, acc[0][3]);
            acc[1][0] = fmaf(av.y, wv.x, acc[1][0]); acc[1][1] = fmaf(av.y, wv.y, acc[1][1]);
            acc[1][2] = fmaf(av.y, wv.z, acc[1][2]); acc[1][3] = fmaf(av.y, wv.w, acc[1][3]);
            acc[2][0] = fmaf(av.z, wv.x, acc[2][0]); acc[2][1] = fmaf(av.z, wv.y, acc[2][1]);
            acc[2][2] = fmaf(av.z, wv.z, acc[2][2]); acc[2][3] = fmaf(av.z, wv.w, acc[2][3]);
            acc[3][0] = fmaf(av.w, wv.x, acc[3][0]); acc[3][1] = fmaf(av.w, wv.y, acc[3][1]);
            acc[3][2] = fmaf(av.w, wv.z, acc[3][2]); acc[3][3] = fmaf(av.w, wv.w, acc[3][3]);
        }
        __syncthreads();
    }
#pragma unroll
    for (int i = 0; i < 4; ++i)
#pragma unroll
        for (int j = 0; j < 4; ++j)
            C[(size_t)(m0 + ty * 4 + i) * 128 + n0 + tx * 4 + j] = acc[i][j];
}

// ---------------- WH2 = dec_Whh + Wih[:,:80] @ mel_W ----------------
__global__ __launch_bounds__(256) void wh2_kernel(const float* __restrict__ Wih,
                                                  const float* __restrict__ Whh,
                                                  const float* __restrict__ melW,
                                                  float* __restrict__ WH2) {
    int wg = blockIdx.x;
    int tid = threadIdx.x;
    int r = wg >> 1;
    int k = (wg & 1) * 256 + tid;
    __shared__ float wrow[80];
    if (tid < 80) wrow[tid] = Wih[(size_t)r * 1104 + tid];
    __syncthreads();
    float acc = Whh[(size_t)r * 512 + k];
#pragma unroll 8
    for (int m = 0; m < 80; ++m)
        acc = fmaf(wrow[m], melW[m * 512 + k], acc);
    WH2[(size_t)r * 512 + k] = acc;
}

// ---------------- biasA = bih+bhh ; biasB = biasA + Wih[:,:80].mel_b ----------------
__global__ __launch_bounds__(256) void bias_kernel(const float* __restrict__ Wih,
                                                   const float* __restrict__ bih,
                                                   const float* __restrict__ bhh,
                                                   const float* __restrict__ melb,
                                                   float* __restrict__ BA,
                                                   float* __restrict__ BB) {
    int r = blockIdx.x * 256 + threadIdx.x;
    float a = bih[r] + bhh[r];
    float b2 = 0.f;
#pragma unroll 8
    for (int m = 0; m < 80; ++m)
        b2 = fmaf(Wih[(size_t)r * 1104 + m], melb[m], b2);
    BA[r] = a;
    BB[r] = a + b2;
}

// ---------------- per-(dir,batch) LSTM (r12/r14, unchanged) ----------------
__global__ __launch_bounds__(256) void lstm_kernel(const float* __restrict__ GXf,
                                                   const float* __restrict__ GXb,
                                                   const float* __restrict__ Whh_f,
                                                   const float* __restrict__ Whh_b,
                                                   float* __restrict__ Hout,
                                                   float* __restrict__ hstate,
                                                   unsigned* __restrict__ flagsL) {
    int wg  = blockIdx.x;
    int s   = wg & 7;
    int g16 = wg >> 3;
    int dir = g16 >> 3;
    int b   = g16 & 7;
    const float* GX  = dir ? GXb : GXf;
    const float* Whh = dir ? Whh_b : Whh_f;
    float* hs = hstate + g16 * 1024;
    unsigned* fg = flagsL + g16 * 128;

    int tid = threadIdx.x;
    int g = tid >> 6, c = tid & 63;
    int grow = g * 512 + s * 64 + c;
    const float* wr = Whh + (size_t)grow * 512;

    __shared__ float hsh[512];
    __shared__ float gvL[4][64];

    float cst = 0.f;

    for (int t = 0; t < 128; ++t) {
        if (tid < 128) {
            const unsigned* f = fg + (tid >> 4) * 16;
            while (agr_u(f) < (unsigned)t)
                __builtin_amdgcn_s_sleep(1);
            *(float4*)&hsh[tid * 4] = agr_f4(hs + (t & 1) * 512 + tid * 4);
        }
        __syncthreads();

        int st = dir ? (127 - t) : t;
        float acc = GX[((size_t)b * S_ + st) * G_ + grow];
        float a0 = 0.f, a1 = 0.f, a2 = 0.f, a3 = 0.f;
#pragma unroll 8
        for (int k = 0; k < 512; k += 4) {
            float4 wv = *(const float4*)(wr + k);
            float4 hv = *(const float4*)&hsh[k];
            a0 = fmaf(wv.x, hv.x, a0); a1 = fmaf(wv.y, hv.y, a1);
            a2 = fmaf(wv.z, hv.z, a2); a3 = fmaf(wv.w, hv.w, a3);
        }
        gvL[g][c] = acc + (a0 + a1) + (a2 + a3);
        __syncthreads();

        if (tid < 64) {
            float gi = gvL[0][tid], gf = gvL[1][tid];
            float gg = gvL[2][tid], go = gvL[3][tid];
            float c2 = sigm_f(gf) * cst + sigm_f(gi) * tanh_f(gg);
            float h2 = sigm_f(go) * tanh_f(c2);
            cst = c2;
            agw_f(hs + ((t & 1) ^ 1) * 512 + s * 64 + tid, h2);
            asm volatile("s_waitcnt vmcnt(0)" ::: "memory");
            if (tid == 0)
                agw_u(fg + s * 16, (unsigned)(t + 1));
            Hout[((size_t)b * S_ + st) * 1024 + dir * 512 + s * 64 + tid] = h2;
        }
    }
}

// ---------------- decoder: 2 edges/step via producer-side hW partials ----------------
// gate WG (b,s): XCD s%8. Owns cols [s*32,(s+1)*32) x 4 gates. At step end it
// computes h2-slice AND its hW partial W_h[:,cols].h2 (64KB L2-hot slice) and
// publishes both: fCh after h store, fCp after partial store.
// attn WG (b): XCD b. Sums 16 partials (batched sc1 loads), scores+softmax -> fB.
// Cycle: fCp -> attn{sum,scores,softmax} -> fB -> gates{WE.att+cell+partials} -> fCp.
// Gates' WH2.h overlaps the attention phase (gated by fCh only).
__global__ __launch_bounds__(256) void decoder_kernel(float* __restrict__ ws,
                                                      const float* __restrict__ attn_W,
                                                      const float* __restrict__ attn_v,
                                                      const float* __restrict__ mel_W,
                                                      const float* __restrict__ mel_b,
                                                      float* __restrict__ out, int T,
                                                      unsigned* __restrict__ flags) {
    float* ENCP = ws + OFF_ENCP;
    float* DH   = ws + OFF_DH;    // [2][8][512]
    float* ATT  = ws + OFF_ATT;   // [8][128]
    float* HWP  = ws + OFF_HWP;   // [8][16][512]
    const float* WE  = ws + OFF_WE;
    const float* WH2 = ws + OFF_WH2;
    const float* BA  = ws + OFF_BA;
    const float* BB  = ws + OFF_BB;

    int wg  = blockIdx.x;
    int tid = threadIdx.x;

    if (wg < 128) {
        // ================= gate WG (slice s, batch b) =================
        int s = wg & 15;
        int b = wg >> 4;
        unsigned* fCh = flags + b * 1024;         // lines 0..15
        unsigned* fCp = fCh + 256;                // lines 16..31
        unsigned* fB  = fCh + 512;                // line 32

        int r   = tid >> 1;                 // local row 0..127
        int half = tid & 1;
        int grow = (r >> 5) * 512 + s * 32 + (r & 31);
        const float* wh2_half = WH2 + (size_t)grow * 512 + half * 256;
        const float* we_row   = WE + ((size_t)b * 2048 + grow) * 128 + half * 64;
        float bias_a = (half == 0) ? BA[grow] : 0.f;
        float bias_b = (half == 0) ? BB[grow] : 0.f;

        __shared__ float hsh[512];
        __shared__ float gBx[128][2];
        __shared__ float gv[128];
        __shared__ float attL[128];
        __shared__ float h2sh[32];

        float cst = 0.f;   // tid<32: col = s*32+tid

        for (int t = 0; t < T; ++t) {
            // ---- stage h_t (per-lane poll on fCh) ----
            if (tid < 128) {
                const unsigned* f = fCh + (tid >> 3) * 16;
                while (agr_u(f) < (unsigned)t)
                    __builtin_amdgcn_s_sleep(1);
                *(float4*)&hsh[tid * 4] = agr_f4(DH + (t & 1) * 4096 + b * 512 + tid * 4);
            }
            __syncthreads();

            // WH2.h (overlaps the attention phase)
            float wpart = (t == 0) ? bias_a : bias_b;
            {
                const float* hp = hsh + half * 256;
                float a0 = 0.f, a1 = 0.f, a2 = 0.f, a3 = 0.f;
#pragma unroll 8
                for (int k = 0; k < 256; k += 4) {
                    float4 wv = *(const float4*)(wh2_half + k);
                    float4 hv = *(const float4*)(hp + k);
                    a0 = fmaf(wv.x, hv.x, a0); a1 = fmaf(wv.y, hv.y, a1);
                    a2 = fmaf(wv.z, hv.z, a2); a3 = fmaf(wv.w, hv.w, a3);
                }
                wpart += (a0 + a1) + (a2 + a3);
            }

            // ---- stage att (single flag) ----
            if (tid < 32) {
                while (agr_u(fB) < (unsigned)(t + 1))
                    __builtin_amdgcn_s_sleep(1);
                *(float4*)&attL[tid * 4] = agr_f4(ATT + b * 128 + tid * 4);
            }
            __syncthreads();

            // WE.att (K=64 per half)
            {
                const float* ap = attL + half * 64;
                float a0 = 0.f, a1 = 0.f, a2 = 0.f, a3 = 0.f;
#pragma unroll 8
                for (int k = 0; k < 64; k += 4) {
                    float4 wv = *(const float4*)(we_row + k);
                    a0 = fmaf(wv.x, ap[k + 0], a0); a1 = fmaf(wv.y, ap[k + 1], a1);
                    a2 = fmaf(wv.z, ap[k + 2], a2); a3 = fmaf(wv.w, ap[k + 3], a3);
                }
                gBx[r][half] = wpart + (a0 + a1) + (a2 + a3);
            }
            __syncthreads();
            if (tid < 128)
                gv[tid] = gBx[tid][0] + gBx[tid][1];
            __syncthreads();

            // cell update + h store + fCh (wave 0)
            if (tid < 32) {
                float gi = gv[tid], gf = gv[32 + tid], gg = gv[64 + tid], go = gv[96 + tid];
                float c2 = sigm_f(gf) * cst + sigm_f(gi) * tanh_f(gg);
                float h2 = sigm_f(go) * tanh_f(c2);
                cst = c2;
                h2sh[tid] = h2;
                agw_f(DH + ((t + 1) & 1) * 4096 + b * 512 + s * 32 + tid, h2);
                asm volatile("s_waitcnt vmcnt(0)" ::: "memory");
                if (tid == 0)
                    agw_u(fCh + s * 16, (unsigned)(t + 1));
            }
            __syncthreads();   // h2sh visible to all

            // hW partial of h2: rows 4*tid..4*tid+3, 32 MACs/row
            if (tid < 128) {
                int r0 = tid * 4;
                float p[4];
#pragma unroll
                for (int i = 0; i < 4; ++i) {
                    const float* wrow2 = attn_W + (size_t)(r0 + i) * 1536 + s * 32;
                    float a0 = 0.f, a1 = 0.f, a2 = 0.f, a3 = 0.f;
#pragma unroll
                    for (int c = 0; c < 32; c += 4) {
                        float4 wv = *(const float4*)(wrow2 + c);
                        a0 = fmaf(wv.x, h2sh[c + 0], a0); a1 = fmaf(wv.y, h2sh[c + 1], a1);
                        a2 = fmaf(wv.z, h2sh[c + 2], a2); a3 = fmaf(wv.w, h2sh[c + 3], a3);
                    }
                    p[i] = (a0 + a1) + (a2 + a3);
                }
                float4 v; v.x = p[0]; v.y = p[1]; v.z = p[2]; v.w = p[3];
                agw_f4(HWP + ((size_t)(b * 16 + s)) * 512 + r0, v);   // embedded drain
            }
            __syncthreads();   // all waves drained their stores
            if (tid == 0)
                agw_u(fCp + s * 16, (unsigned)(t + 1));
        }
    } else {
        // ================= attention WG (batch b) =================
        int b = wg - 128;
        unsigned* fCh = flags + b * 1024;
        unsigned* fCp = fCh + 256;
        unsigned* fB  = fCh + 512;

        __shared__ float hwp2[2][512];
        __shared__ float hw2[512];
        __shared__ float dh2[512];
        __shared__ float scred[128][2];
        __shared__ float red[128];
        __shared__ float att[128];
        __shared__ float melp[80][2];

        int r = tid >> 1, half = tid & 1;

        for (int t = 0; t < T; ++t) {
            // poll all 16 fCp (partials of h_t ready)
            if (tid < 16) {
                while (agr_u(fCp + tid * 16) < (unsigned)t)
                    __builtin_amdgcn_s_sleep(1);
            }
            __syncthreads();

            // stage + partial-sum HWP: thread owns f4-chunk c4=(tid&127), j-half jh=tid>>7
            {
                int c4 = (tid & 127), jh = tid >> 7;
                const float* base = HWP + (size_t)b * 8192 + (size_t)jh * 8 * 512 + c4 * 4;
                float4 v0, v1, v2, v3, v4, v5, v6, v7;
                agr_f4x4(base + 0 * 512, base + 1 * 512, base + 2 * 512, base + 3 * 512,
                         v0, v1, v2, v3);
                agr_f4x4(base + 4 * 512, base + 5 * 512, base + 6 * 512, base + 7 * 512,
                         v4, v5, v6, v7);
                float4 sum;
                sum.x = ((v0.x + v1.x) + (v2.x + v3.x)) + ((v4.x + v5.x) + (v6.x + v7.x));
                sum.y = ((v0.y + v1.y) + (v2.y + v3.y)) + ((v4.y + v5.y) + (v6.y + v7.y));
                sum.z = ((v0.z + v1.z) + (v2.z + v3.z)) + ((v4.z + v5.z) + (v6.z + v7.z));
                sum.w = ((v0.w + v1.w) + (v2.w + v3.w)) + ((v4.w + v5.w) + (v6.w + v7.w));
                *(float4*)&hwp2[jh][c4 * 4] = sum;
            }
            __syncthreads();
            if (tid < 128) {
                float4 a = *(const float4*)&hwp2[0][tid * 4];
                float4 c = *(const float4*)&hwp2[1][tid * 4];
                float4 s4; s4.x = a.x + c.x; s4.y = a.y + c.y; s4.z = a.z + c.z; s4.w = a.w + c.w;
                *(float4*)&hw2[tid * 4] = s4;
            }
            __syncthreads();

            // scores: sI = tid&127, k-half = tid>>7
            {
                int sI = tid & 127, kh = tid >> 7;
                const float* ep = ENCP + ((size_t)b * S_ + sI) * 512 + kh * 256;
                const float* hp = hw2 + kh * 256;
                const float* vv = attn_v + kh * 256;
                float a0 = 0.f, a1 = 0.f, a2 = 0.f, a3 = 0.f;
#pragma unroll 4
                for (int k = 0; k < 256; k += 4) {
                    float4 e4 = *(const float4*)(ep + k);
                    float4 h4 = *(const float4*)(hp + k);
                    float4 v4 = *(const float4*)(vv + k);
                    a0 = fmaf(tanh_f(e4.x + h4.x), v4.x, a0);
                    a1 = fmaf(tanh_f(e4.y + h4.y), v4.y, a1);
                    a2 = fmaf(tanh_f(e4.z + h4.z), v4.z, a2);
                    a3 = fmaf(tanh_f(e4.w + h4.w), v4.w, a3);
                }
                scred[sI][kh] = (a0 + a1) + (a2 + a3);
            }
            __syncthreads();

            float sc = 0.f;
            if (tid < 128) {
                sc = scred[tid][0] + scred[tid][1];
                red[tid] = sc;
            }
            __syncthreads();
            for (int off = 64; off >= 1; off >>= 1) {
                if (tid < off) red[tid] = fmaxf(red[tid], red[tid + off]);
                __syncthreads();
            }
            float mx = red[0];
            __syncthreads();
            if (tid < 128) {
                float e = __expf(sc - mx);
                att[tid] = e;
                red[tid] = e;
            }
            __syncthreads();
            if (tid < 64) red[tid] += red[tid + 64];
            __syncthreads();
            for (int off = 32; off >= 1; off >>= 1) {
                if (tid < off) red[tid] += red[tid + off];
                __syncthreads();
            }
            float inv = 1.f / red[0];

            // att write + fast flag (wave 0)
            if (tid < 32) {
                agw_f(ATT + b * 128 + tid * 4 + 0, att[tid * 4 + 0] * inv);
                agw_f(ATT + b * 128 + tid * 4 + 1, att[tid * 4 + 1] * inv);
                agw_f(ATT + b * 128 + tid * 4 + 2, att[tid * 4 + 2] * inv);
                agw_f(ATT + b * 128 + tid * 4 + 3, att[tid * 4 + 3] * inv);
                asm volatile("s_waitcnt vmcnt(0)" ::: "memory");
                if (tid == 0)
                    agw_u(fB, (unsigned)(t + 1));
            }

            // ---- off-critical-path: mel from h_t -> out[t-1] ----
            if (t > 0) {
                if (tid < 128)
                    *(float4*)&dh2[tid * 4] = agr_f4(DH + (t & 1) * 4096 + b * 512 + tid * 4);
                __syncthreads();
                if (tid < 160) {
                    const float* wp = mel_W + (size_t)r * 512 + half * 256;
                    const float* hp = dh2 + half * 256;
                    float a0 = 0.f, a1 = 0.f, a2 = 0.f, a3 = 0.f;
#pragma unroll 8
                    for (int k = 0; k < 256; k += 4) {
                        float4 wv = *(const float4*)(wp + k);
                        float4 hv = *(const float4*)(hp + k);
                        a0 = fmaf(wv.x, hv.x, a0); a1 = fmaf(wv.y, hv.y, a1);
                        a2 = fmaf(wv.z, hv.z, a2); a3 = fmaf(wv.w, hv.w, a3);
                    }
                    melp[r][half] = (a0 + a1) + (a2 + a3);
                }
                __syncthreads();
                if (tid < 80)
                    out[b * MEL_ * T + tid * T + (t - 1)] = melp[tid][0] + melp[tid][1] + mel_b[tid];
            } else {
                __syncthreads();
            }
        }

        // epilogue: final mel from h_T -> out[T-1]
        if (tid < 16) {
            while (agr_u(fCh + tid * 16) < (unsigned)T)
                __builtin_amdgcn_s_sleep(1);
        }
        __syncthreads();
        if (tid < 128)
            *(float4*)&dh2[tid * 4] = agr_f4(DH + (T & 1) * 4096 + b * 512 + tid * 4);
        __syncthreads();
        if (tid < 160) {
            const float* wp = mel_W + (size_t)r * 512 + half * 256;
            const float* hp = dh2 + half * 256;
            float a0 = 0.f, a1 = 0.f, a2 = 0.f, a3 = 0.f;
#pragma unroll 8
            for (int k = 0; k < 256; k += 4) {
                float4 wv = *(const float4*)(wp + k);
                float4 hv = *(const float4*)(hp + k);
                a0 = fmaf(wv.x, hv.x, a0); a1 = fmaf(wv.y, hv.y, a1);
                a2 = fmaf(wv.z, hv.z, a2); a3 = fmaf(wv.w, hv.w, a3);
            }
            melp[r][half] = (a0 + a1) + (a2 + a3);
        }
        __syncthreads();
        if (tid < 80)
            out[b * MEL_ * T + tid * T + (T - 1)] = melp[tid][0] + melp[tid][1] + mel_b[tid];
    }
}

// ---------------- host launch ----------------
extern "C" void kernel_launch(void* const* d_in, const int* in_sizes, int n_in,
                              void* d_out, int out_size, void* d_ws, size_t ws_size,
                              hipStream_t stream) {
    const int*   text  = (const int*)d_in[0];
    const float* emb   = (const float*)d_in[2];
    const float* Wih00 = (const float*)d_in[3];
    const float* Whh00 = (const float*)d_in[4];
    const float* bih00 = (const float*)d_in[5];
    const float* bhh00 = (const float*)d_in[6];
    const float* Wih01 = (const float*)d_in[7];
    const float* Whh01 = (const float*)d_in[8];
    const float* bih01 = (const float*)d_in[9];
    const float* bhh01 = (const float*)d_in[10];
    const float* Wih10 = (const float*)d_in[11];
    const float* Whh10 = (const float*)d_in[12];
    const float* bih10 = (const float*)d_in[13];
    const float* bhh10 = (const float*)d_in[14];
    const float* Wih11 = (const float*)d_in[15];
    const float* Whh11 = (const float*)d_in[16];
    const float* bih11 = (const float*)d_in[17];
    const float* bhh11 = (const float*)d_in[18];
    const float* attn_W = (const float*)d_in[19];
    const float* attn_b = (const float*)d_in[20];
    const float* attn_v = (const float*)d_in[21];
    const float* dec_Wih = (const float*)d_in[22];
    const float* dec_Whh = (const float*)d_in[23];
    const float* dec_bih = (const float*)d_in[24];
    const float* dec_bhh = (const float*)d_in[25];
    const float* mel_W = (const float*)d_in[26];
    const float* mel_b = (const float*)d_in[27];

    float* ws = (float*)d_ws;
    unsigned* flags = (unsigned*)d_ws;
    float* out = (float*)d_out;
    int T = out_size / (B_ * MEL_);   // 200

    // zero flags + recurrent state
    zero_kernel<<<ZERO_WORDS / 256, 256, 0, stream>>>(ws);

    // embedding
    embed_kernel<<<512, 256, 0, stream>>>(text, emb, ws + OFF_X0);

    // layer0 input projections (bias folded: bih + bhh)
    gemm_f32<<<dim3(32, 16), 256, 0, stream>>>(ws + OFF_X0, 512, Wih00, 512,
                                               bih00, bhh00, ws + OFF_GX0F, 2048, 512);
    gemm_f32<<<dim3(32, 16), 256, 0, stream>>>(ws + OFF_X0, 512, Wih01, 512,
                                               bih01, bhh01, ws + OFF_GX0B, 2048, 512);
    // layer0 recurrence
    lstm_kernel<<<128, 256, 0, stream>>>(ws + OFF_GX0F, ws + OFF_GX0B, Whh00, Whh01,
                                         ws + OFF_H0, ws + OFF_H0S, flags + FLG_L0);
    // decoder weight folds (GX0B dead now)
    wh2_kernel<<<4096, 256, 0, stream>>>(dec_Wih, dec_Whh, mel_W, ws + OFF_WH2);
    bias_kernel<<<8, 256, 0, stream>>>(dec_Wih, dec_bih, dec_bhh, mel_b,
                                       ws + OFF_BA, ws + OFF_BB);
    // layer1 input projections
    gemm_f32<<<dim3(32, 16), 256, 0, stream>>>(ws + OFF_H0, 1024, Wih10, 1024,
                                               bih10, bhh10, ws + OFF_GX1F, 2048, 1024);
    gemm_f32<<<dim3(32, 16), 256, 0, stream>>>(ws + OFF_H0, 1024, Wih11, 1024,
                                               bih11, bhh11, ws + OFF_GX1B, 2048, 1024);
    // layer1 recurrence -> enc
    lstm_kernel<<<128, 256, 0, stream>>>(ws + OFF_GX1F, ws + OFF_GX1B, Whh10, Whh11,
                                         ws + OFF_ENC, ws + OFF_H1S, flags + FLG_L1);
    // enc_part = enc @ W_e^T + attn_b
    gemm_f32<<<dim3(8, 16), 256, 0, stream>>>(ws + OFF_ENC, 1024, attn_W + 512, 1536,
                                              attn_b, nullptr, ws + OFF_ENCP, 512, 1024);
    // WE[b] = Wih_ctx @ ENC_b^T (GX0F dead now)
    we_kernel<<<dim3(2, 32, 8), 256, 0, stream>>>(dec_Wih, ws + OFF_ENC, ws + OFF_WE);
    // HWP zero (GX1F dead after lstm1; h_0 = 0 -> partials must start at 0)
    zero_kernel<<<65536 / 256, 256, 0, stream>>>(ws + OFF_HWP);
    // decoder: 128 gate WGs + 8 attention WGs, 2 edges/step
    decoder_kernel<<<136, 256, 0, stream>>>(ws, attn_W, attn_v, mel_W, mel_b, out, T,
                                            flags + FLG_DEC);
}